// Round 2
// baseline (454.301 us; speedup 1.0000x reference)
//
#include <hip/hip_runtime.h>
#include <hip/hip_bf16.h>
#include <hip/hip_fp8.h>
#include <cstdint>
#include <cstddef>

typedef __hip_bfloat16 bf16;
typedef unsigned char fp8;                                  // e4m3 storage
typedef __attribute__((ext_vector_type(8))) short short8;   // 8 bf16 (MFMA A/B frag)
typedef __attribute__((ext_vector_type(4))) float f32x4;    // MFMA C/D frag
typedef __attribute__((ext_vector_type(2))) float f32x2;

#define NSF 128
#define BN_EPS 1e-3f
#define NR 4            // src ranges per node
#define SCK 2048        // elements per scan block

// ---------------- CSR build: 1 atomic per edge ----------------

__global__ void passA_kernel(const int* __restrict__ ei, int* __restrict__ fill,
                             int* __restrict__ loc, int E, int n, int rsize) {
    int idx = blockIdx.x * blockDim.x + threadIdx.x;
    if (idx < E) {
        int r = ei[idx];
        int c = ei[E + idx];
        int slot = c * NR + r / rsize;
        loc[idx] = atomicAdd(&fill[slot], 1);
    } else if (idx < E + n) {
        int i = idx - E;
        int slot = i * NR + i / rsize;
        loc[idx] = atomicAdd(&fill[slot], 1);
    }
}

// ---- hierarchical exclusive scan of fill -> row_ptr ----

__global__ void scan1_kernel(const int* __restrict__ cnt, int* __restrict__ blksum, int total) {
    __shared__ int red[256];
    int base = blockIdx.x * SCK + threadIdx.x * 8;
    int s = 0;
    #pragma unroll
    for (int i = 0; i < 8; ++i) {
        int idx = base + i;
        if (idx < total) s += cnt[idx];
    }
    red[threadIdx.x] = s;
    __syncthreads();
    for (int off2 = 128; off2 > 0; off2 >>= 1) {
        if (threadIdx.x < off2) red[threadIdx.x] += red[threadIdx.x + off2];
        __syncthreads();
    }
    if (threadIdx.x == 0) blksum[blockIdx.x] = red[0];
}

__global__ void scan2_kernel(int* __restrict__ blksum, int* __restrict__ row_ptr,
                             int nblk, int total) {
    __shared__ int part[256];
    int tid = threadIdx.x;
    int v = (tid < nblk) ? blksum[tid] : 0;
    part[tid] = v;
    __syncthreads();
    for (int off2 = 1; off2 < 256; off2 <<= 1) {
        int t = (tid >= off2) ? part[tid - off2] : 0;
        __syncthreads();
        part[tid] += t;
        __syncthreads();
    }
    if (tid < nblk) blksum[tid] = part[tid] - v;
    if (tid == 255) row_ptr[total] = part[255];
}

__global__ void scan3_kernel(const int* __restrict__ cnt, const int* __restrict__ blkoff,
                             int* __restrict__ row_ptr, int total) {
    __shared__ int part[256];
    int tid = threadIdx.x;
    int base = blockIdx.x * SCK + tid * 8;
    int loc[8]; int s = 0;
    #pragma unroll
    for (int i = 0; i < 8; ++i) {
        int idx = base + i;
        loc[i] = (idx < total) ? cnt[idx] : 0;
        s += loc[i];
    }
    part[tid] = s;
    __syncthreads();
    for (int off2 = 1; off2 < 256; off2 <<= 1) {
        int t = (tid >= off2) ? part[tid - off2] : 0;
        __syncthreads();
        part[tid] += t;
        __syncthreads();
    }
    int run = blkoff[blockIdx.x] + part[tid] - s;
    #pragma unroll
    for (int i = 0; i < 8; ++i) {
        int idx = base + i;
        if (idx < total) { row_ptr[idx] = run; run += loc[i]; }
    }
}

// passB: scatter without atomics; packed edge record {src, w_bits}
__global__ void passB_kernel(const int* __restrict__ ei, const float* __restrict__ ea,
                             const int* __restrict__ row_ptr, const int* __restrict__ loc,
                             int2* __restrict__ e8, int* __restrict__ csr_col,
                             int E, int n, int rsize) {
    int idx = blockIdx.x * blockDim.x + threadIdx.x;
    if (idx < E) {
        int r = ei[idx];
        int c = ei[E + idx];
        int slot = c * NR + r / rsize;
        int p = row_ptr[slot] + loc[idx];
        int2 rec; rec.x = r; rec.y = __float_as_int(ea[idx]);
        e8[p] = rec;
        csr_col[p] = c;
    } else if (idx < E + n) {
        int i = idx - E;
        int slot = i * NR + i / rsize;
        int p = row_ptr[slot] + loc[idx];
        int2 rec; rec.x = i; rec.y = __float_as_int(1.0f);
        e8[p] = rec;
        csr_col[p] = i;
    }
}

__global__ void degdinv_kernel(const int* __restrict__ row_ptr, const int2* __restrict__ e8,
                               float* __restrict__ dinv, int n) {
    int node = blockIdx.x * blockDim.x + threadIdx.x;
    if (node < n) {
        int s = row_ptr[node * NR], e = row_ptr[(node + 1) * NR];
        float d = 0.0f;
        for (int j = s; j < e; ++j) d += __int_as_float(e8[j].y);
        dinv[node] = (d > 0.0f) ? rsqrtf(d) : 0.0f;
    }
}

__global__ void normw_kernel(const float* __restrict__ dinv, const int* __restrict__ csr_col,
                             int2* __restrict__ e8, int EN) {
    int p = blockIdx.x * blockDim.x + threadIdx.x;
    if (p < EN) {
        int2 rec = e8[p];
        float w = dinv[rec.x] * __int_as_float(rec.y) * dinv[csr_col[p]];
        ((int*)e8)[2 * p + 1] = __float_as_int(w);
    }
}

// ---------------- output-type helpers (HW fp8 cvt) ----------------

__device__ inline void store_val(bf16* C, size_t idx, float a) {
    C[idx] = __float2bfloat16(a);
}
__device__ inline void store_val(fp8* C, size_t idx, float a) {
    int packed = __builtin_amdgcn_cvt_pk_fp8_f32(a, a, 0, false);
    C[idx] = (fp8)(packed & 0xff);
}

// ---------------- fused prep: zero fill[] + x->fp8 + all W->Wt(bf16), one launch ----------------
__global__ void prep_kernel(int* __restrict__ fill, int total,
                            const float* __restrict__ x, fp8* __restrict__ xq, int xcnt,
                            const float* __restrict__ W0, const float* __restrict__ W1,
                            const float* __restrict__ W2, const float* __restrict__ W3,
                            const float* __restrict__ W4,
                            bf16* __restrict__ wtbuf, int wtelems) {
    int idx = blockIdx.x * blockDim.x + threadIdx.x;
    if (idx < total) { fill[idx] = 0; return; }
    idx -= total;
    if (idx < xcnt) {
        store_val(xq, idx, x[idx]);
        return;
    }
    int widx = idx - xcnt;
    if (widx >= wtelems) return;
    // layer boundaries (cumulative K*N): 32768, 163840, 294912, 327680, 344064
    const float* W; int K, off;
    if (widx < 32768)       { W = W0; K = 128; off = 0; }
    else if (widx < 163840) { W = W1; K = 256; off = 32768; }
    else if (widx < 294912) { W = W2; K = 512; off = 163840; }
    else if (widx < 327680) { W = W3; K = 256; off = 294912; }
    else                    { W = W4; K = 128; off = 327680; }
    int N2;
    if (widx < 32768) N2 = 256; else if (widx < 163840) N2 = 512;
    else if (widx < 294912) N2 = 256; else N2 = 128;
    int l = widx - off;
    int nn = l / K, kk = l % K;
    wtbuf[widx] = __float2bfloat16(W[(size_t)kk * N2 + nn]);
}

// ---------------- direct global->LDS 16B staging ----------------

__device__ inline void gl_lds16(const bf16* g, bf16* l) {
    __builtin_amdgcn_global_load_lds(
        (const __attribute__((address_space(1))) void*)g,
        (__attribute__((address_space(3))) void*)l,
        16, 0, 0);
}

// ---------------- MFMA GEMM: C[M,N] = A[M,K] @ Wt[N,K]^T, fused epilogue ----------------
// mode 0: raw store; mode 1: sigmoid(BN(acc+bias))

template <typename OT>
__global__ __launch_bounds__(256) void mfma_gemm_kernel(
    const bf16* __restrict__ A, const bf16* __restrict__ Wt,
    OT* __restrict__ C, int M, int K, int N, int mode,
    const float* __restrict__ bias, const float* __restrict__ g,
    const float* __restrict__ be, const float* __restrict__ m,
    const float* __restrict__ v) {
    __shared__ bf16 As[64][32];
    __shared__ bf16 Bs[128][32];
    int m0 = blockIdx.x * 64;
    int n0 = blockIdx.y * 128;
    int tid = threadIdx.x;
    int wave = tid >> 6, lane = tid & 63;
    int lrow = lane & 15, quad = lane >> 4;

    f32x4 acc[4][2] = {};   // [m-tile][n-tile]

    int srow = lane >> 2;
    int sseg = lane & 3;
    int am = wave * 16 + srow;
    int bn = wave * 32 + srow;
    bool aok = (m0 + am) < M;

    for (int k0 = 0; k0 < K; k0 += 32) {
        if (aok)
            gl_lds16(A + (size_t)(m0 + am) * K + k0 + sseg * 8, &As[am][sseg * 8]);
        gl_lds16(Wt + (size_t)(n0 + bn) * K + k0 + sseg * 8, &Bs[bn][sseg * 8]);
        gl_lds16(Wt + (size_t)(n0 + bn + 16) * K + k0 + sseg * 8, &Bs[bn + 16][sseg * 8]);
        __syncthreads();

        short8 afrag[4], bfrag[2];
        #pragma unroll
        for (int mt = 0; mt < 4; ++mt)
            afrag[mt] = *(const short8*)(&As[mt * 16 + lrow][quad * 8]);
        #pragma unroll
        for (int nt = 0; nt < 2; ++nt)
            bfrag[nt] = *(const short8*)(&Bs[wave * 32 + nt * 16 + lrow][quad * 8]);
        #pragma unroll
        for (int mt = 0; mt < 4; ++mt)
            #pragma unroll
            for (int nt = 0; nt < 2; ++nt)
                acc[mt][nt] = __builtin_amdgcn_mfma_f32_16x16x32_bf16(
                    afrag[mt], bfrag[nt], acc[mt][nt], 0, 0, 0);
        __syncthreads();
    }
    // C/D: col = lane&15, row = quad*4 + reg
    #pragma unroll
    for (int nt = 0; nt < 2; ++nt) {
        int gn = n0 + wave * 32 + nt * 16 + lrow;
        float bsc = 0.0f, scale = 1.0f, mean = 0.0f, beta = 0.0f;
        if (mode == 1) {
            bsc = bias[gn];
            scale = g[gn] * rsqrtf(v[gn] + BN_EPS);
            mean = m[gn];
            beta = be[gn];
        }
        #pragma unroll
        for (int mt = 0; mt < 4; ++mt) {
            #pragma unroll
            for (int rr = 0; rr < 4; ++rr) {
                int gm = m0 + mt * 16 + quad * 4 + rr;
                if (gm < M) {
                    float a = acc[mt][nt][rr];
                    if (mode == 1) {
                        a = (a + bsc - mean) * scale + beta;
                        a = 1.0f / (1.0f + __expf(-a));
                    }
                    store_val(C, (size_t)gm * N + gn, a);
                }
            }
        }
    }
}

// ---------------- fp8 aggregation: multi-edge-per-instruction gathers ----------------
// Round 17 redesign. Evidence: agg<2> (1 line/edge) == agg<4> (2 lines/edge) duration,
// and 2x deeper pipelining was ~null -> the cap is per-WAVE-INSTRUCTION vmem overhead,
// not line bandwidth. So pack many edges into ONE gather instruction via per-lane
// addresses: VEC=2 (row=128B): 8 lanes x 16B per edge -> 8 edges/instr; VEC=4
// (row=256B): 16 lanes x 16B -> 4 edges/instr. Each lane accumulates 16 features
// (acc[16], statically indexed). After the edge loop a shfl_xor all-reduce across
// edge-groups merges partials; group-0 lanes apply bias/BN/sigmoid and store
// 16 bf16 each. Records still cooperatively staged to a per-wave LDS strip.
// 4 named uint4 buffers keep 4 gather instrs (=16/32 edges) in flight.

template <int VEC> struct AggCfg;
template <> struct AggCfg<2> { static const int EPI = 8; static const int LPE = 8;  };
template <> struct AggCfg<4> { static const int EPI = 4; static const int LPE = 16; };

__device__ inline void fma16_f8(uint4 q, float w, float* acc) {
    const unsigned* qq = reinterpret_cast<const unsigned*>(&q);
    #pragma unroll
    for (int c = 0; c < 4; ++c) {
        f32x2 lo = __builtin_amdgcn_cvt_pk_f32_fp8(qq[c], false);
        f32x2 hi = __builtin_amdgcn_cvt_pk_f32_fp8(qq[c], true);
        acc[c * 4 + 0] += w * lo.x;
        acc[c * 4 + 1] += w * lo.y;
        acc[c * 4 + 2] += w * hi.x;
        acc[c * 4 + 3] += w * hi.y;
    }
}

template <int VEC>
__global__ __launch_bounds__(256) void agg_fp8_kernel(
    const fp8* __restrict__ hw,
    const int* __restrict__ row_ptr, const int2* __restrict__ e8,
    const float* __restrict__ bias,
    const float* __restrict__ g, const float* __restrict__ be,
    const float* __restrict__ m, const float* __restrict__ v,
    bf16* __restrict__ out, int n, int mode) {
    const int dfeat = VEC * 64;
    const int EPI = AggCfg<VEC>::EPI;   // edges per gather instruction
    const int LPE = AggCfg<VEC>::LPE;   // lanes per edge
    __shared__ int2 recs[4][64];
    int wave = threadIdx.x >> 6;
    int lane = threadIdx.x & 63;
    int node = blockIdx.x * 4 + wave;
    if (node >= n) return;
    int s = row_ptr[node * NR], e = row_ptr[(node + 1) * NR];
    int grp = lane / LPE;               // edge-group 0..EPI-1
    int sub = lane % LPE;               // sub-lane within edge (16B slice)

    float acc[16];
    #pragma unroll
    for (int k = 0; k < 16; ++k) acc[k] = 0.0f;

    const fp8* hw_base = hw + sub * 16; // lane's 16B slice offset within a row

#define LOADI(Q, WV, T)                                                       \
    {                                                                         \
        int2 rc = recs[wave][(T) * EPI + grp];                                \
        WV = __int_as_float(rc.y);                                            \
        Q = *(const uint4*)(hw_base + ((size_t)(unsigned)rc.x * dfeat));      \
    }
#define CONSI(Q, WV) fma16_f8(Q, WV, acc);

    for (int cs = s; cs < e; cs += 64) {
        int cnt = e - cs; if (cnt > 64) cnt = 64;
        // cooperative coalesced record load; pad with {src=0, w=0}
        int2 r0; r0.x = 0; r0.y = 0;
        if (lane < cnt) r0 = e8[cs + lane];
        recs[wave][lane] = r0;
        // wave-local fence: only this wave touches recs[wave][*]
        asm volatile("s_waitcnt vmcnt(0) lgkmcnt(0)" ::: "memory");

        int ni = (cnt + EPI - 1) / EPI;        // gather instrs needed
        int ni4 = (ni + 3) & ~3;               // round to pipeline quantum (<= 64/EPI)

        uint4 qA, qB, qC, qD;
        float wA, wB, wC, wD;
        LOADI(qA, wA, 0)
        LOADI(qB, wB, 1)
        LOADI(qC, wC, 2)
        LOADI(qD, wD, 3)
        for (int t = 4; t < ni4; t += 4) {
            CONSI(qA, wA) LOADI(qA, wA, t)
            CONSI(qB, wB) LOADI(qB, wB, t + 1)
            CONSI(qC, wC) LOADI(qC, wC, t + 2)
            CONSI(qD, wD) LOADI(qD, wD, t + 3)
        }
        CONSI(qA, wA)
        CONSI(qB, wB)
        CONSI(qC, wC)
        CONSI(qD, wD)
    }
#undef LOADI
#undef CONSI

    // all-reduce partial sums across edge-groups (lanes sharing `sub`)
    #pragma unroll
    for (int k = 0; k < 16; ++k) {
        float vsum = acc[k];
        if (EPI == 8) vsum += __shfl_xor(vsum, 8);
        vsum += __shfl_xor(vsum, 16);
        vsum += __shfl_xor(vsum, 32);
        acc[k] = vsum;
    }

    if (grp == 0) {
        int f0 = sub * 16;
        bf16 ob[16];
        #pragma unroll
        for (int k = 0; k < 16; ++k) {
            int f = f0 + k;
            float a = acc[k];
            if (mode != 0) {
                a += bias[f];
                if (mode == 1) {
                    float scale = g[f] * rsqrtf(v[f] + BN_EPS);
                    a = (a - m[f]) * scale + be[f];
                }
                a = 1.0f / (1.0f + __expf(-a));
            }
            ob[k] = __float2bfloat16(a);
        }
        bf16* op = out + (size_t)node * dfeat + f0;
        *(uint4*)(op) = *(const uint4*)(&ob[0]);
        *(uint4*)(op + 8) = *(const uint4*)(&ob[8]);
    }
}

// ---------------- final h^T h via MFMA ----------------
#define TPAD 8

__global__ __launch_bounds__(256) void htht_mfma_kernel(
    const bf16* __restrict__ h, float* __restrict__ partial, int n) {
    __shared__ bf16 hsT[128][32 + TPAD];
    int b = blockIdx.x;
    int tid = threadIdx.x;
    int wave = tid >> 6, lane = tid & 63;
    int lrow = lane & 15, quad = lane >> 4;

    f32x4 acc[2][8] = {};

    int kk = tid >> 3;
    int seg = tid & 7;

    for (int kt = 0; kt < 8; ++kt) {
        int k0 = b * 256 + kt * 32;
        #pragma unroll
        for (int s2 = 0; s2 < 2; ++s2) {
            int fs = (seg + s2 * 8) * 8;
            int gk = k0 + kk;
            uint4 q; q.x = q.y = q.z = q.w = 0u;
            if (gk < n) q = *(const uint4*)(h + (size_t)gk * 128 + fs);
            const unsigned short* u = (const unsigned short*)&q;
            #pragma unroll
            for (int i = 0; i < 8; ++i)
                *((unsigned short*)&hsT[fs + i][kk]) = u[i];
        }
        __syncthreads();
        short8 af0 = *(const short8*)(&hsT[wave * 32 + lrow][quad * 8]);
        short8 af1 = *(const short8*)(&hsT[wave * 32 + 16 + lrow][quad * 8]);
        #pragma unroll
        for (int t = 0; t < 8; ++t) {
            short8 bfrag = *(const short8*)(&hsT[t * 16 + lrow][quad * 8]);
            acc[0][t] = __builtin_amdgcn_mfma_f32_16x16x32_bf16(af0, bfrag, acc[0][t], 0, 0, 0);
            acc[1][t] = __builtin_amdgcn_mfma_f32_16x16x32_bf16(af1, bfrag, acc[1][t], 0, 0, 0);
        }
        __syncthreads();
    }
    float* p = partial + (size_t)b * 16384;
    #pragma unroll
    for (int a_ = 0; a_ < 2; ++a_) {
        #pragma unroll
        for (int t = 0; t < 8; ++t) {
            #pragma unroll
            for (int rr = 0; rr < 4; ++rr) {
                int gm = wave * 32 + a_ * 16 + quad * 4 + rr;
                int gn = t * 16 + lrow;
                p[gm * 128 + gn] = acc[a_][t][rr];
            }
        }
    }
}

__global__ void reduce_kernel(const float* __restrict__ partial, float* __restrict__ out, int nchunks) {
    int idx = blockIdx.x * blockDim.x + threadIdx.x;
    float s = 0.0f;
    for (int c = 0; c < nchunks; ++c) s += partial[(size_t)c * 16384 + idx];
    int i = idx / 128, j = idx % 128;
    out[idx] = (i == j) ? 0.0f : s;
}

// ---------------- launch ----------------
extern "C" void kernel_launch(void* const* d_in, const int* in_sizes, int n_in,
                              void* d_out, int out_size, void* d_ws, size_t ws_size,
                              hipStream_t stream) {
    const float* x  = (const float*)d_in[0];
    const int*   ei = (const int*)d_in[1];
    const float* ea = (const float*)d_in[2];
    const float* W[5];  const float* bvec[5];
    for (int l = 0; l < 5; ++l) { W[l] = (const float*)d_in[3 + 2 * l]; bvec[l] = (const float*)d_in[4 + 2 * l]; }
    const float* g[4]; const float* be[4]; const float* mm[4]; const float* vv[4];
    for (int l = 0; l < 4; ++l) {
        g[l]  = (const float*)d_in[13 + 4 * l];
        be[l] = (const float*)d_in[14 + 4 * l];
        mm[l] = (const float*)d_in[15 + 4 * l];
        vv[l] = (const float*)d_in[16 + 4 * l];
    }
    const int n = in_sizes[0] / NSF;        // 20000
    const int E = in_sizes[1] / 2;          // 500000
    const int EN = E + n;
    const int rsize = (n + NR - 1) / NR;
    const int total = n * NR;
    const int nscan = (total + SCK - 1) / SCK;
    const int dims[6] = {128, 256, 512, 256, 128, 128};
    const int wtoff[5] = {0, 32768, 163840, 294912, 327680};
    const int wtelems = 344064;

    // workspace layout (256B aligned); ~69 MB
    auto align = [](size_t o) { return (o + 255) & ~(size_t)255; };
    size_t off = 0;
    float* dinv    = (float*)((char*)d_ws + off); off = align(off + (size_t)n * 4);
    int*   fill    = (int*)  ((char*)d_ws + off); off = align(off + (size_t)total * 4);
    int*   row_ptr = (int*)  ((char*)d_ws + off); off = align(off + ((size_t)total + 1) * 4);
    int*   blksum  = (int*)  ((char*)d_ws + off); off = align(off + (size_t)256 * 4);
    int*   locb    = (int*)  ((char*)d_ws + off); off = align(off + (size_t)EN * 4);
    int2*  e8      = (int2*) ((char*)d_ws + off); off = align(off + (size_t)EN * 8);
    int*   csr_col = (int*)  ((char*)d_ws + off); off = align(off + (size_t)EN * 4);
    bf16*  wtbuf   = (bf16*) ((char*)d_ws + off); off = align(off + (size_t)wtelems * 2);
    fp8*   xq      = (fp8*)  ((char*)d_ws + off); off = align(off + (size_t)n * 128);
    bf16*  hbuf    = (bf16*) ((char*)d_ws + off); off = align(off + (size_t)n * 512 * 2);
    bf16*  abuf    = (bf16*) ((char*)d_ws + off); off = align(off + (size_t)n * 512 * 2);
    fp8*   f8buf   = (fp8*)  ((char*)d_ws + off); off = align(off + (size_t)n * 256);
    const int KCH = (20000 + 255) / 256;    // 79
    float* partial = (float*)((char*)d_ws + off); off = align(off + (size_t)KCH * 16384 * 4);

    // fused prep: zero fill + x->fp8 + W->Wt (one launch, independent of edges)
    {
        int xcnt = n * 128;
        int items = total + xcnt + wtelems;
        prep_kernel<<<(items + 255) / 256, 256, 0, stream>>>(fill, total, x, xq, xcnt,
            W[0], W[1], W[2], W[3], W[4], wtbuf, wtelems);
    }

    // CSR build (1 atomic/edge, packed edge records)
    passA_kernel<<<(EN + 255) / 256, 256, 0, stream>>>(ei, fill, locb, E, n, rsize);
    scan1_kernel<<<nscan, 256, 0, stream>>>(fill, blksum, total);
    scan2_kernel<<<1, 256, 0, stream>>>(blksum, row_ptr, nscan, total);
    scan3_kernel<<<nscan, 256, 0, stream>>>(fill, blksum, row_ptr, total);
    passB_kernel<<<(EN + 255) / 256, 256, 0, stream>>>(ei, ea, row_ptr, locb,
                                                       e8, csr_col, E, n, rsize);
    degdinv_kernel<<<(n + 255) / 256, 256, 0, stream>>>(row_ptr, e8, dinv, n);
    normw_kernel<<<(EN + 255) / 256, 256, 0, stream>>>(dinv, csr_col, e8, EN);

    int ablocks = (n + 3) / 4;
    auto gemm_bf16 = [&](const bf16* A, int l, bf16* C, int mode) {
        int K = dims[l], N = dims[l + 1];
        dim3 gg((n + 63) / 64, N / 128);
        int bi = (l < 4) ? l : 0;
        mfma_gemm_kernel<bf16><<<gg, 256, 0, stream>>>(A, wtbuf + wtoff[l], C, n, K, N, mode,
                                                       bvec[l], g[bi], be[bi], mm[bi], vv[bi]);
    };
    auto gemm_fp8 = [&](const bf16* A, int l, fp8* C, int mode) {
        int K = dims[l], N = dims[l + 1];
        dim3 gg((n + 63) / 64, N / 128);
        int bi = (l < 4) ? l : 0;
        mfma_gemm_kernel<fp8><<<gg, 256, 0, stream>>>(A, wtbuf + wtoff[l], C, n, K, N, mode,
                                                      bvec[l], g[bi], be[bi], mm[bi], vv[bi]);
    };

    // L1 (128->256): agg-first fp8 128 (xq), GEMM1 fused act -> fp8 h1
    agg_fp8_kernel<2><<<ablocks, 256, 0, stream>>>(xq, row_ptr, e8,
        bvec[0], bvec[0], bvec[0], bvec[0], bvec[0], abuf, n, 0);
    gemm_fp8(abuf, 0, f8buf, 1);
    // L2 (256->512): agg-first fp8 256 (h1) -> bf16, GEMM2 fused act -> bf16 h2 (512)
    agg_fp8_kernel<4><<<ablocks, 256, 0, stream>>>(f8buf, row_ptr, e8,
        bvec[1], bvec[1], bvec[1], bvec[1], bvec[1], abuf, n, 0);
    gemm_bf16(abuf, 1, hbuf, 1);
    // L3 (512->256): GEMM3 raw -> fp8 hw3, agg-last fp8 256 + bias+BN+sigmoid -> bf16 h3
    gemm_fp8(hbuf, 2, f8buf, 0);
    agg_fp8_kernel<4><<<ablocks, 256, 0, stream>>>(f8buf, row_ptr, e8,
        bvec[2], g[2], be[2], mm[2], vv[2], abuf, n, 1);
    // L4 (256->128): GEMM4 raw -> fp8 hw4, agg-last fp8 128 + bias+BN+sigmoid -> bf16 h4
    gemm_fp8(abuf, 3, f8buf, 0);
    agg_fp8_kernel<2><<<ablocks, 256, 0, stream>>>(f8buf, row_ptr, e8,
        bvec[3], g[3], be[3], mm[3], vv[3], hbuf, n, 1);
    // L5 (128->128): GEMM5 raw -> fp8 hw5, agg-last fp8 128 + bias+sigmoid -> bf16 h5
    gemm_fp8(hbuf, 4, f8buf, 0);
    agg_fp8_kernel<2><<<ablocks, 256, 0, stream>>>(f8buf, row_ptr, e8,
        bvec[4], bvec[4], bvec[4], bvec[4], bvec[4], abuf, n, 2);

    // final h^T h with zeroed diagonal (MFMA)
    htht_mfma_kernel<<<KCH, 256, 0, stream>>>(abuf, partial, n);
    reduce_kernel<<<16384 / 256, 256, 0, stream>>>(partial, (float*)d_out, KCH);
}

// Round 4
// 398.508 us; speedup vs baseline: 1.1400x; 1.1400x over previous
//
#include <hip/hip_runtime.h>
#include <hip/hip_bf16.h>
#include <hip/hip_fp8.h>
#include <cstdint>
#include <cstddef>
#include <cstring>

typedef __hip_bfloat16 bf16;
typedef unsigned char fp8;                                  // e4m3 storage
typedef __attribute__((ext_vector_type(8))) short short8;   // 8 bf16 (MFMA A/B frag)
typedef __attribute__((ext_vector_type(4))) float f32x4;    // MFMA C/D frag
typedef __attribute__((ext_vector_type(2))) float f32x2;

#define NSF 128
#define BN_EPS 1e-3f
#define NR 8            // src ranges per node (finer slab -> better L2 phase locality)
#define SCK 2048        // elements per scan block

// ---------------- non-temporal helpers (keep L2 for gather targets) ----------------

__device__ inline int2 ldnt_int2(const int2* p) {
    unsigned long long v = __builtin_nontemporal_load((const unsigned long long*)p);
    int2 r; r.x = (int)(unsigned)(v & 0xffffffffull); r.y = (int)(unsigned)(v >> 32);
    return r;
}

// ---------------- CSR build: 1 atomic per edge ----------------

__global__ void passA_kernel(const int* __restrict__ ei, int* __restrict__ fill,
                             int* __restrict__ loc, int E, int n, int rsize) {
    int idx = blockIdx.x * blockDim.x + threadIdx.x;
    if (idx < E) {
        int r = ei[idx];
        int c = ei[E + idx];
        int slot = c * NR + r / rsize;
        loc[idx] = atomicAdd(&fill[slot], 1);
    } else if (idx < E + n) {
        int i = idx - E;
        int slot = i * NR + i / rsize;
        loc[idx] = atomicAdd(&fill[slot], 1);
    }
}

// ---- hierarchical exclusive scan of fill -> row_ptr ----

__global__ void scan1_kernel(const int* __restrict__ cnt, int* __restrict__ blksum, int total) {
    __shared__ int red[256];
    int base = blockIdx.x * SCK + threadIdx.x * 8;
    int s = 0;
    #pragma unroll
    for (int i = 0; i < 8; ++i) {
        int idx = base + i;
        if (idx < total) s += cnt[idx];
    }
    red[threadIdx.x] = s;
    __syncthreads();
    for (int off2 = 128; off2 > 0; off2 >>= 1) {
        if (threadIdx.x < off2) red[threadIdx.x] += red[threadIdx.x + off2];
        __syncthreads();
    }
    if (threadIdx.x == 0) blksum[blockIdx.x] = red[0];
}

__global__ void scan2_kernel(int* __restrict__ blksum, int* __restrict__ row_ptr,
                             int nblk, int total) {
    __shared__ int part[256];
    int tid = threadIdx.x;
    int v = (tid < nblk) ? blksum[tid] : 0;
    part[tid] = v;
    __syncthreads();
    for (int off2 = 1; off2 < 256; off2 <<= 1) {
        int t = (tid >= off2) ? part[tid - off2] : 0;
        __syncthreads();
        part[tid] += t;
        __syncthreads();
    }
    if (tid < nblk) blksum[tid] = part[tid] - v;
    if (tid == 255) row_ptr[total] = part[255];
}

__global__ void scan3_kernel(const int* __restrict__ cnt, const int* __restrict__ blkoff,
                             int* __restrict__ row_ptr, int total) {
    __shared__ int part[256];
    int tid = threadIdx.x;
    int base = blockIdx.x * SCK + tid * 8;
    int loc[8]; int s = 0;
    #pragma unroll
    for (int i = 0; i < 8; ++i) {
        int idx = base + i;
        loc[i] = (idx < total) ? cnt[idx] : 0;
        s += loc[i];
    }
    part[tid] = s;
    __syncthreads();
    for (int off2 = 1; off2 < 256; off2 <<= 1) {
        int t = (tid >= off2) ? part[tid - off2] : 0;
        __syncthreads();
        part[tid] += t;
        __syncthreads();
    }
    int run = blkoff[blockIdx.x] + part[tid] - s;
    #pragma unroll
    for (int i = 0; i < 8; ++i) {
        int idx = base + i;
        if (idx < total) { row_ptr[idx] = run; run += loc[i]; }
    }
}

// passB: scatter without atomics; packed edge record {src, w_bits}
__global__ void passB_kernel(const int* __restrict__ ei, const float* __restrict__ ea,
                             const int* __restrict__ row_ptr, const int* __restrict__ loc,
                             int2* __restrict__ e8, int* __restrict__ csr_col,
                             int E, int n, int rsize) {
    int idx = blockIdx.x * blockDim.x + threadIdx.x;
    if (idx < E) {
        int r = ei[idx];
        int c = ei[E + idx];
        int slot = c * NR + r / rsize;
        int p = row_ptr[slot] + loc[idx];
        int2 rec; rec.x = r; rec.y = __float_as_int(ea[idx]);
        e8[p] = rec;
        csr_col[p] = c;
    } else if (idx < E + n) {
        int i = idx - E;
        int slot = i * NR + i / rsize;
        int p = row_ptr[slot] + loc[idx];
        int2 rec; rec.x = i; rec.y = __float_as_int(1.0f);
        e8[p] = rec;
        csr_col[p] = i;
    }
}

__global__ void degdinv_kernel(const int* __restrict__ row_ptr, const int2* __restrict__ e8,
                               float* __restrict__ dinv, int n) {
    int node = blockIdx.x * blockDim.x + threadIdx.x;
    if (node < n) {
        int s = row_ptr[node * NR], e = row_ptr[(node + 1) * NR];
        float d = 0.0f;
        for (int j = s; j < e; ++j) d += __int_as_float(e8[j].y);
        dinv[node] = (d > 0.0f) ? rsqrtf(d) : 0.0f;
    }
}

__global__ void normw_kernel(const float* __restrict__ dinv, const int* __restrict__ csr_col,
                             int2* __restrict__ e8, int EN) {
    int p = blockIdx.x * blockDim.x + threadIdx.x;
    if (p < EN) {
        int2 rec = e8[p];
        float w = dinv[rec.x] * __int_as_float(rec.y) * dinv[csr_col[p]];
        ((int*)e8)[2 * p + 1] = __float_as_int(w);
    }
}

// ---------------- output-type helpers (HW fp8 cvt) ----------------

__device__ inline void store_val(bf16* C, size_t idx, float a) {
    C[idx] = __float2bfloat16(a);
}
__device__ inline void store_val(fp8* C, size_t idx, float a) {
    int packed = __builtin_amdgcn_cvt_pk_fp8_f32(a, a, 0, false);
    C[idx] = (fp8)(packed & 0xff);
}

// ---------------- fused prep: zero fill[] + x->fp8 + all W->Wt(bf16), one launch ----------------
__global__ void prep_kernel(int* __restrict__ fill, int total,
                            const float* __restrict__ x, fp8* __restrict__ xq, int xcnt,
                            const float* __restrict__ W0, const float* __restrict__ W1,
                            const float* __restrict__ W2, const float* __restrict__ W3,
                            const float* __restrict__ W4,
                            bf16* __restrict__ wtbuf, int wtelems) {
    int idx = blockIdx.x * blockDim.x + threadIdx.x;
    if (idx < total) { fill[idx] = 0; return; }
    idx -= total;
    if (idx < xcnt) {
        store_val(xq, idx, x[idx]);
        return;
    }
    int widx = idx - xcnt;
    if (widx >= wtelems) return;
    // layer boundaries (cumulative K*N): 32768, 163840, 294912, 327680, 344064
    const float* W; int K, off;
    if (widx < 32768)       { W = W0; K = 128; off = 0; }
    else if (widx < 163840) { W = W1; K = 256; off = 32768; }
    else if (widx < 294912) { W = W2; K = 512; off = 163840; }
    else if (widx < 327680) { W = W3; K = 256; off = 294912; }
    else                    { W = W4; K = 128; off = 327680; }
    int N2;
    if (widx < 32768) N2 = 256; else if (widx < 163840) N2 = 512;
    else if (widx < 294912) N2 = 256; else N2 = 128;
    int l = widx - off;
    int nn = l / K, kk = l % K;
    wtbuf[widx] = __float2bfloat16(W[(size_t)kk * N2 + nn]);
}

// ---------------- direct global->LDS 16B staging ----------------

__device__ inline void gl_lds16(const bf16* g, bf16* l) {
    __builtin_amdgcn_global_load_lds(
        (const __attribute__((address_space(1))) void*)g,
        (__attribute__((address_space(3))) void*)l,
        16, 0, 0);
}

// ---------------- MFMA GEMM: C[M,N] = A[M,K] @ Wt[N,K]^T, fused epilogue ----------------
// mode 0: raw store; mode 1: sigmoid(BN(acc+bias))

template <typename OT>
__global__ __launch_bounds__(256) void mfma_gemm_kernel(
    const bf16* __restrict__ A, const bf16* __restrict__ Wt,
    OT* __restrict__ C, int M, int K, int N, int mode,
    const float* __restrict__ bias, const float* __restrict__ g,
    const float* __restrict__ be, const float* __restrict__ m,
    const float* __restrict__ v) {
    __shared__ bf16 As[64][32];
    __shared__ bf16 Bs[128][32];
    int m0 = blockIdx.x * 64;
    int n0 = blockIdx.y * 128;
    int tid = threadIdx.x;
    int wave = tid >> 6, lane = tid & 63;
    int lrow = lane & 15, quad = lane >> 4;

    f32x4 acc[4][2] = {};   // [m-tile][n-tile]

    int srow = lane >> 2;
    int sseg = lane & 3;
    int am = wave * 16 + srow;
    int bn = wave * 32 + srow;
    bool aok = (m0 + am) < M;

    for (int k0 = 0; k0 < K; k0 += 32) {
        if (aok)
            gl_lds16(A + (size_t)(m0 + am) * K + k0 + sseg * 8, &As[am][sseg * 8]);
        gl_lds16(Wt + (size_t)(n0 + bn) * K + k0 + sseg * 8, &Bs[bn][sseg * 8]);
        gl_lds16(Wt + (size_t)(n0 + bn + 16) * K + k0 + sseg * 8, &Bs[bn + 16][sseg * 8]);
        __syncthreads();

        short8 afrag[4], bfrag[2];
        #pragma unroll
        for (int mt = 0; mt < 4; ++mt)
            afrag[mt] = *(const short8*)(&As[mt * 16 + lrow][quad * 8]);
        #pragma unroll
        for (int nt = 0; nt < 2; ++nt)
            bfrag[nt] = *(const short8*)(&Bs[wave * 32 + nt * 16 + lrow][quad * 8]);
        #pragma unroll
        for (int mt = 0; mt < 4; ++mt)
            #pragma unroll
            for (int nt = 0; nt < 2; ++nt)
                acc[mt][nt] = __builtin_amdgcn_mfma_f32_16x16x32_bf16(
                    afrag[mt], bfrag[nt], acc[mt][nt], 0, 0, 0);
        __syncthreads();
    }
    // C/D: col = lane&15, row = quad*4 + reg
    #pragma unroll
    for (int nt = 0; nt < 2; ++nt) {
        int gn = n0 + wave * 32 + nt * 16 + lrow;
        float bsc = 0.0f, scale = 1.0f, mean = 0.0f, beta = 0.0f;
        if (mode == 1) {
            bsc = bias[gn];
            scale = g[gn] * rsqrtf(v[gn] + BN_EPS);
            mean = m[gn];
            beta = be[gn];
        }
        #pragma unroll
        for (int mt = 0; mt < 4; ++mt) {
            #pragma unroll
            for (int rr = 0; rr < 4; ++rr) {
                int gm = m0 + mt * 16 + quad * 4 + rr;
                if (gm < M) {
                    float a = acc[mt][nt][rr];
                    if (mode == 1) {
                        a = (a + bsc - mean) * scale + beta;
                        a = 1.0f / (1.0f + __expf(-a));
                    }
                    store_val(C, (size_t)gm * N + gn, a);
                }
            }
        }
    }
}

// ---------------- fp8 aggregation: LDS-staged records + 2-deep pipelined gathers ----------------
// Round-18/19: round-1 coalesced one-row-per-instruction gather structure
// (round-2 multi-row packing hit the address-divergence worst case, -80%).
// e8 record stream loaded NON-TEMPORAL and outputs stored NON-TEMPORAL so the
// per-XCD L2 keeps the gather-target rows resident (FETCH_SIZE showed ~55% L2 hit on
// a set that nominally fits -> stream-induced thrash).

template <int VEC> struct F8Vec;
template <> struct F8Vec<2> { typedef unsigned short T; };
template <> struct F8Vec<4> { typedef unsigned int T; };

__device__ inline void fma_f8(unsigned short q, float w, float* acc) {
    f32x2 lo = __builtin_amdgcn_cvt_pk_f32_fp8((unsigned int)q, false);
    acc[0] += w * lo.x;
    acc[1] += w * lo.y;
}
__device__ inline void fma_f8(unsigned int q, float w, float* acc) {
    f32x2 lo = __builtin_amdgcn_cvt_pk_f32_fp8(q, false);
    f32x2 hi = __builtin_amdgcn_cvt_pk_f32_fp8(q, true);
    acc[0] += w * lo.x;
    acc[1] += w * lo.y;
    acc[2] += w * hi.x;
    acc[3] += w * hi.y;
}

template <int VEC>
__global__ __launch_bounds__(256) void agg_fp8_kernel(
    const fp8* __restrict__ hw,
    const int* __restrict__ row_ptr, const int2* __restrict__ e8,
    const float* __restrict__ bias,
    const float* __restrict__ g, const float* __restrict__ be,
    const float* __restrict__ m, const float* __restrict__ v,
    bf16* __restrict__ out, int n, int mode) {
    typedef typename F8Vec<VEC>::T T;
    const int dfeat = VEC * 64;
    __shared__ int2 recs[4][64];
    int wave = threadIdx.x >> 6;
    int lane = threadIdx.x & 63;
    int node = blockIdx.x * 4 + wave;
    if (node >= n) return;
    int s = row_ptr[node * NR], e = row_ptr[(node + 1) * NR];
    float acc[VEC];
    #pragma unroll
    for (int i = 0; i < VEC; ++i) acc[i] = 0.0f;
    const unsigned int base = (unsigned int)lane * VEC;

#define LOADG(Q, WV, J0)                                                     \
    _Pragma("unroll")                                                        \
    for (int u = 0; u < 8; ++u) {                                            \
        int2 rec = recs[wave][(J0) + u];                                     \
        WV[u] = __int_as_float(rec.y);                                       \
        Q[u] = *(const T*)(hw + ((unsigned int)rec.x * dfeat + base));       \
    }
#define CONSUME(Q, WV)                                                       \
    _Pragma("unroll")                                                        \
    for (int u = 0; u < 8; ++u) fma_f8(Q[u], WV[u], acc);

    for (int cs = s; cs < e; cs += 64) {
        int cnt = e - cs; if (cnt > 64) cnt = 64;
        // cooperative coalesced record load (non-temporal: each record read once);
        // pad with {src=0, w=0}
        int2 r0; r0.x = 0; r0.y = 0;
        if (lane < cnt) r0 = ldnt_int2(&e8[cs + lane]);
        recs[wave][lane] = r0;
        // wave-local fence: only this wave touches recs[wave][*]
        asm volatile("s_waitcnt vmcnt(0) lgkmcnt(0)" ::: "memory");

        int npad = (cnt + 15) & ~15;   // >= 16
        T qA[8], qB[8];
        float wA[8], wB[8];
        LOADG(qA, wA, 0)
        LOADG(qB, wB, 8)
        for (int j0 = 16; j0 < npad; j0 += 16) {
            CONSUME(qA, wA)            // waits vmcnt(8): B still in flight
            LOADG(qA, wA, j0)
            CONSUME(qB, wB)
            LOADG(qB, wB, j0 + 8)
        }
        CONSUME(qA, wA)
        CONSUME(qB, wB)
    }
#undef LOADG
#undef CONSUME

    // epilogue + packed non-temporal store (output is streamed by the next GEMM)
    unsigned short us[4];
    #pragma unroll
    for (int i = 0; i < VEC; ++i) {
        int f = (int)base + i;
        float a = acc[i];
        if (mode != 0) {
            a += bias[f];
            if (mode == 1) {
                float scale = g[f] * rsqrtf(v[f] + BN_EPS);
                a = (a - m[f]) * scale + be[f];
            }
            a = 1.0f / (1.0f + __expf(-a));
        }
        bf16 b = __float2bfloat16(a);
        unsigned short ub;
        __builtin_memcpy(&ub, &b, 2);
        us[i] = ub;
    }
    bf16* op = out + (size_t)node * dfeat + base;
    if (VEC == 2) {
        unsigned int w0 = (unsigned int)us[0] | ((unsigned int)us[1] << 16);
        __builtin_nontemporal_store(w0, (unsigned int*)op);
    } else {
        unsigned long long w64 =
            (unsigned long long)us[0] | ((unsigned long long)us[1] << 16) |
            ((unsigned long long)us[2] << 32) | ((unsigned long long)us[3] << 48);
        __builtin_nontemporal_store(w64, (unsigned long long*)op);
    }
}

// ---------------- final h^T h via MFMA ----------------
#define TPAD 8

__global__ __launch_bounds__(256) void htht_mfma_kernel(
    const bf16* __restrict__ h, float* __restrict__ partial, int n) {
    __shared__ bf16 hsT[128][32 + TPAD];
    int b = blockIdx.x;
    int tid = threadIdx.x;
    int wave = tid >> 6, lane = tid & 63;
    int lrow = lane & 15, quad = lane >> 4;

    f32x4 acc[2][8] = {};

    int kk = tid >> 3;
    int seg = tid & 7;

    for (int kt = 0; kt < 8; ++kt) {
        int k0 = b * 256 + kt * 32;
        #pragma unroll
        for (int s2 = 0; s2 < 2; ++s2) {
            int fs = (seg + s2 * 8) * 8;
            int gk = k0 + kk;
            uint4 q; q.x = q.y = q.z = q.w = 0u;
            if (gk < n) q = *(const uint4*)(h + (size_t)gk * 128 + fs);
            const unsigned short* u = (const unsigned short*)&q;
            #pragma unroll
            for (int i = 0; i < 8; ++i)
                *((unsigned short*)&hsT[fs + i][kk]) = u[i];
        }
        __syncthreads();
        short8 af0 = *(const short8*)(&hsT[wave * 32 + lrow][quad * 8]);
        short8 af1 = *(const short8*)(&hsT[wave * 32 + 16 + lrow][quad * 8]);
        #pragma unroll
        for (int t = 0; t < 8; ++t) {
            short8 bfrag = *(const short8*)(&hsT[t * 16 + lrow][quad * 8]);
            acc[0][t] = __builtin_amdgcn_mfma_f32_16x16x32_bf16(af0, bfrag, acc[0][t], 0, 0, 0);
            acc[1][t] = __builtin_amdgcn_mfma_f32_16x16x32_bf16(af1, bfrag, acc[1][t], 0, 0, 0);
        }
        __syncthreads();
    }
    float* p = partial + (size_t)b * 16384;
    #pragma unroll
    for (int a_ = 0; a_ < 2; ++a_) {
        #pragma unroll
        for (int t = 0; t < 8; ++t) {
            #pragma unroll
            for (int rr = 0; rr < 4; ++rr) {
                int gm = wave * 32 + a_ * 16 + quad * 4 + rr;
                int gn = t * 16 + lrow;
                __builtin_nontemporal_store(acc[a_][t][rr], &p[gm * 128 + gn]);
            }
        }
    }
}

__global__ void reduce_kernel(const float* __restrict__ partial, float* __restrict__ out, int nchunks) {
    int idx = blockIdx.x * blockDim.x + threadIdx.x;
    float s = 0.0f;
    for (int c = 0; c < nchunks; ++c)
        s += __builtin_nontemporal_load(&partial[(size_t)c * 16384 + idx]);
    int i = idx / 128, j = idx % 128;
    out[idx] = (i == j) ? 0.0f : s;
}

// ---------------- launch ----------------
extern "C" void kernel_launch(void* const* d_in, const int* in_sizes, int n_in,
                              void* d_out, int out_size, void* d_ws, size_t ws_size,
                              hipStream_t stream) {
    const float* x  = (const float*)d_in[0];
    const int*   ei = (const int*)d_in[1];
    const float* ea = (const float*)d_in[2];
    const float* W[5];  const float* bvec[5];
    for (int l = 0; l < 5; ++l) { W[l] = (const float*)d_in[3 + 2 * l]; bvec[l] = (const float*)d_in[4 + 2 * l]; }
    const float* g[4]; const float* be[4]; const float* mm[4]; const float* vv[4];
    for (int l = 0; l < 4; ++l) {
        g[l]  = (const float*)d_in[13 + 4 * l];
        be[l] = (const float*)d_in[14 + 4 * l];
        mm[l] = (const float*)d_in[15 + 4 * l];
        vv[l] = (const float*)d_in[16 + 4 * l];
    }
    const int n = in_sizes[0] / NSF;        // 20000
    const int E = in_sizes[1] / 2;          // 500000
    const int EN = E + n;
    const int rsize = (n + NR - 1) / NR;
    const int total = n * NR;
    const int nscan = (total + SCK - 1) / SCK;
    const int dims[6] = {128, 256, 512, 256, 128, 128};
    const int wtoff[5] = {0, 32768, 163840, 294912, 327680};
    const int wtelems = 344064;

    // workspace layout (256B aligned); ~69 MB
    auto align = [](size_t o) { return (o + 255) & ~(size_t)255; };
    size_t off = 0;
    float* dinv    = (float*)((char*)d_ws + off); off = align(off + (size_t)n * 4);
    int*   fill    = (int*)  ((char*)d_ws + off); off = align(off + (size_t)total * 4);
    int*   row_ptr = (int*)  ((char*)d_ws + off); off = align(off + ((size_t)total + 1) * 4);
    int*   blksum  = (int*)  ((char*)d_ws + off); off = align(off + (size_t)256 * 4);
    int*   locb    = (int*)  ((char*)d_ws + off); off = align(off + (size_t)EN * 4);
    int2*  e8      = (int2*) ((char*)d_ws + off); off = align(off + (size_t)EN * 8);
    int*   csr_col = (int*)  ((char*)d_ws + off); off = align(off + (size_t)EN * 4);
    bf16*  wtbuf   = (bf16*) ((char*)d_ws + off); off = align(off + (size_t)wtelems * 2);
    fp8*   xq      = (fp8*)  ((char*)d_ws + off); off = align(off + (size_t)n * 128);
    bf16*  hbuf    = (bf16*) ((char*)d_ws + off); off = align(off + (size_t)n * 512 * 2);
    bf16*  abuf    = (bf16*) ((char*)d_ws + off); off = align(off + (size_t)n * 512 * 2);
    fp8*   f8buf   = (fp8*)  ((char*)d_ws + off); off = align(off + (size_t)n * 256);
    const int KCH = (20000 + 255) / 256;    // 79
    float* partial = (float*)((char*)d_ws + off); off = align(off + (size_t)KCH * 16384 * 4);

    // fused prep: zero fill + x->fp8 + W->Wt (one launch, independent of edges)
    {
        int xcnt = n * 128;
        int items = total + xcnt + wtelems;
        prep_kernel<<<(items + 255) / 256, 256, 0, stream>>>(fill, total, x, xq, xcnt,
            W[0], W[1], W[2], W[3], W[4], wtbuf, wtelems);
    }

    // CSR build (1 atomic/edge, packed edge records)
    passA_kernel<<<(EN + 255) / 256, 256, 0, stream>>>(ei, fill, locb, E, n, rsize);
    scan1_kernel<<<nscan, 256, 0, stream>>>(fill, blksum, total);
    scan2_kernel<<<1, 256, 0, stream>>>(blksum, row_ptr, nscan, total);
    scan3_kernel<<<nscan, 256, 0, stream>>>(fill, blksum, row_ptr, total);
    passB_kernel<<<(EN + 255) / 256, 256, 0, stream>>>(ei, ea, row_ptr, locb,
                                                       e8, csr_col, E, n, rsize);
    degdinv_kernel<<<(n + 255) / 256, 256, 0, stream>>>(row_ptr, e8, dinv, n);
    normw_kernel<<<(EN + 255) / 256, 256, 0, stream>>>(dinv, csr_col, e8, EN);

    int ablocks = (n + 3) / 4;
    auto gemm_bf16 = [&](const bf16* A, int l, bf16* C, int mode) {
        int K = dims[l], N = dims[l + 1];
        dim3 gg((n + 63) / 64, N / 128);
        int bi = (l < 4) ? l : 0;
        mfma_gemm_kernel<bf16><<<gg, 256, 0, stream>>>(A, wtbuf + wtoff[l], C, n, K, N, mode,
                                                       bvec[l], g[bi], be[bi], mm[bi], vv[bi]);
    };
    auto gemm_fp8 = [&](const bf16* A, int l, fp8* C, int mode) {
        int K = dims[l], N = dims[l + 1];
        dim3 gg((n + 63) / 64, N / 128);
        int bi = (l < 4) ? l : 0;
        mfma_gemm_kernel<fp8><<<gg, 256, 0, stream>>>(A, wtbuf + wtoff[l], C, n, K, N, mode,
                                                      bvec[l], g[bi], be[bi], mm[bi], vv[bi]);
    };

    // L1 (128->256): agg-first fp8 128 (xq), GEMM1 fused act -> fp8 h1
    agg_fp8_kernel<2><<<ablocks, 256, 0, stream>>>(xq, row_ptr, e8,
        bvec[0], bvec[0], bvec[0], bvec[0], bvec[0], abuf, n, 0);
    gemm_fp8(abuf, 0, f8buf, 1);
    // L2 (256->512): agg-first fp8 256 (h1) -> bf16, GEMM2 fused act -> bf16 h2 (512)
    agg_fp8_kernel<4><<<ablocks, 256, 0, stream>>>(f8buf, row_ptr, e8,
        bvec[1], bvec[1], bvec[1], bvec[1], bvec[1], abuf, n, 0);
    gemm_bf16(abuf, 1, hbuf, 1);
    // L3 (512->256): GEMM3 raw -> fp8 hw3, agg-last fp8 256 + bias+BN+sigmoid -> bf16 h3
    gemm_fp8(hbuf, 2, f8buf, 0);
    agg_fp8_kernel<4><<<ablocks, 256, 0, stream>>>(f8buf, row_ptr, e8,
        bvec[2], g[2], be[2], mm[2], vv[2], abuf, n, 1);
    // L4 (256->128): GEMM4 raw -> fp8 hw4, agg-last fp8 128 + bias+BN+sigmoid -> bf16 h4
    gemm_fp8(abuf, 3, f8buf, 0);
    agg_fp8_kernel<2><<<ablocks, 256, 0, stream>>>(f8buf, row_ptr, e8,
        bvec[3], g[3], be[3], mm[3], vv[3], hbuf, n, 1);
    // L5 (128->128): GEMM5 raw -> fp8 hw5, agg-last fp8 128 + bias+sigmoid -> bf16 h5
    gemm_fp8(hbuf, 4, f8buf, 0);
    agg_fp8_kernel<2><<<ablocks, 256, 0, stream>>>(f8buf, row_ptr, e8,
        bvec[4], bvec[4], bvec[4], bvec[4], bvec[4], abuf, n, 2);

    // final h^T h with zeroed diagonal (MFMA)
    htht_mfma_kernel<<<KCH, 256, 0, stream>>>(abuf, partial, n);
    reduce_kernel<<<16384 / 256, 256, 0, stream>>>(partial, (float*)d_out, KCH);
}

// Round 5
// 394.260 us; speedup vs baseline: 1.1523x; 1.0108x over previous
//
#include <hip/hip_runtime.h>
#include <hip/hip_bf16.h>
#include <hip/hip_fp8.h>
#include <cstdint>
#include <cstddef>
#include <cstring>

typedef __hip_bfloat16 bf16;
typedef unsigned char fp8;                                  // e4m3 storage
typedef __attribute__((ext_vector_type(8))) short short8;   // 8 bf16 (MFMA A/B frag)
typedef __attribute__((ext_vector_type(4))) float f32x4;    // MFMA C/D frag
typedef __attribute__((ext_vector_type(2))) float f32x2;

#define NSF 128
#define BN_EPS 1e-3f
#define NR 4            // src ranges per node
#define SCK 2048        // elements per scan block

// ---------------- CSR build: 1 atomic per edge ----------------

__global__ void passA_kernel(const int* __restrict__ ei, int* __restrict__ fill,
                             int* __restrict__ loc, int E, int n, int rsize) {
    int idx = blockIdx.x * blockDim.x + threadIdx.x;
    if (idx < E) {
        int r = ei[idx];
        int c = ei[E + idx];
        int slot = c * NR + r / rsize;
        loc[idx] = atomicAdd(&fill[slot], 1);
    } else if (idx < E + n) {
        int i = idx - E;
        int slot = i * NR + i / rsize;
        loc[idx] = atomicAdd(&fill[slot], 1);
    }
}

// ---- hierarchical exclusive scan of fill -> row_ptr ----

__global__ void scan1_kernel(const int* __restrict__ cnt, int* __restrict__ blksum, int total) {
    __shared__ int red[256];
    int base = blockIdx.x * SCK + threadIdx.x * 8;
    int s = 0;
    #pragma unroll
    for (int i = 0; i < 8; ++i) {
        int idx = base + i;
        if (idx < total) s += cnt[idx];
    }
    red[threadIdx.x] = s;
    __syncthreads();
    for (int off2 = 128; off2 > 0; off2 >>= 1) {
        if (threadIdx.x < off2) red[threadIdx.x] += red[threadIdx.x + off2];
        __syncthreads();
    }
    if (threadIdx.x == 0) blksum[blockIdx.x] = red[0];
}

__global__ void scan2_kernel(int* __restrict__ blksum, int* __restrict__ row_ptr,
                             int nblk, int total) {
    __shared__ int part[256];
    int tid = threadIdx.x;
    int v = (tid < nblk) ? blksum[tid] : 0;
    part[tid] = v;
    __syncthreads();
    for (int off2 = 1; off2 < 256; off2 <<= 1) {
        int t = (tid >= off2) ? part[tid - off2] : 0;
        __syncthreads();
        part[tid] += t;
        __syncthreads();
    }
    if (tid < nblk) blksum[tid] = part[tid] - v;
    if (tid == 255) row_ptr[total] = part[255];
}

__global__ void scan3_kernel(const int* __restrict__ cnt, const int* __restrict__ blkoff,
                             int* __restrict__ row_ptr, int total) {
    __shared__ int part[256];
    int tid = threadIdx.x;
    int base = blockIdx.x * SCK + tid * 8;
    int loc[8]; int s = 0;
    #pragma unroll
    for (int i = 0; i < 8; ++i) {
        int idx = base + i;
        loc[i] = (idx < total) ? cnt[idx] : 0;
        s += loc[i];
    }
    part[tid] = s;
    __syncthreads();
    for (int off2 = 1; off2 < 256; off2 <<= 1) {
        int t = (tid >= off2) ? part[tid - off2] : 0;
        __syncthreads();
        part[tid] += t;
        __syncthreads();
    }
    int run = blkoff[blockIdx.x] + part[tid] - s;
    #pragma unroll
    for (int i = 0; i < 8; ++i) {
        int idx = base + i;
        if (idx < total) { row_ptr[idx] = run; run += loc[i]; }
    }
}

// passB: scatter without atomics; packed edge record {src, w_bits}
__global__ void passB_kernel(const int* __restrict__ ei, const float* __restrict__ ea,
                             const int* __restrict__ row_ptr, const int* __restrict__ loc,
                             int2* __restrict__ e8, int* __restrict__ csr_col,
                             int E, int n, int rsize) {
    int idx = blockIdx.x * blockDim.x + threadIdx.x;
    if (idx < E) {
        int r = ei[idx];
        int c = ei[E + idx];
        int slot = c * NR + r / rsize;
        int p = row_ptr[slot] + loc[idx];
        int2 rec; rec.x = r; rec.y = __float_as_int(ea[idx]);
        e8[p] = rec;
        csr_col[p] = c;
    } else if (idx < E + n) {
        int i = idx - E;
        int slot = i * NR + i / rsize;
        int p = row_ptr[slot] + loc[idx];
        int2 rec; rec.x = i; rec.y = __float_as_int(1.0f);
        e8[p] = rec;
        csr_col[p] = i;
    }
}

__global__ void degdinv_kernel(const int* __restrict__ row_ptr, const int2* __restrict__ e8,
                               float* __restrict__ dinv, int n) {
    int node = blockIdx.x * blockDim.x + threadIdx.x;
    if (node < n) {
        int s = row_ptr[node * NR], e = row_ptr[(node + 1) * NR];
        float d = 0.0f;
        for (int j = s; j < e; ++j) d += __int_as_float(e8[j].y);
        dinv[node] = (d > 0.0f) ? rsqrtf(d) : 0.0f;
    }
}

__global__ void normw_kernel(const float* __restrict__ dinv, const int* __restrict__ csr_col,
                             int2* __restrict__ e8, int EN) {
    int p = blockIdx.x * blockDim.x + threadIdx.x;
    if (p < EN) {
        int2 rec = e8[p];
        float w = dinv[rec.x] * __int_as_float(rec.y) * dinv[csr_col[p]];
        ((int*)e8)[2 * p + 1] = __float_as_int(w);
    }
}

// ---------------- output-type helpers (HW fp8 cvt) ----------------

__device__ inline void store_val(bf16* C, size_t idx, float a) {
    C[idx] = __float2bfloat16(a);
}
__device__ inline void store_val(fp8* C, size_t idx, float a) {
    int packed = __builtin_amdgcn_cvt_pk_fp8_f32(a, a, 0, false);
    C[idx] = (fp8)(packed & 0xff);
}

// ---------------- fused prep: zero fill[] + x->fp8 + all W->Wt(bf16), one launch ----------------
__global__ void prep_kernel(int* __restrict__ fill, int total,
                            const float* __restrict__ x, fp8* __restrict__ xq, int xcnt,
                            const float* __restrict__ W0, const float* __restrict__ W1,
                            const float* __restrict__ W2, const float* __restrict__ W3,
                            const float* __restrict__ W4,
                            bf16* __restrict__ wtbuf, int wtelems) {
    int idx = blockIdx.x * blockDim.x + threadIdx.x;
    if (idx < total) { fill[idx] = 0; return; }
    idx -= total;
    if (idx < xcnt) {
        store_val(xq, idx, x[idx]);
        return;
    }
    int widx = idx - xcnt;
    if (widx >= wtelems) return;
    // layer boundaries (cumulative K*N): 32768, 163840, 294912, 327680, 344064
    const float* W; int K, off;
    if (widx < 32768)       { W = W0; K = 128; off = 0; }
    else if (widx < 163840) { W = W1; K = 256; off = 32768; }
    else if (widx < 294912) { W = W2; K = 512; off = 163840; }
    else if (widx < 327680) { W = W3; K = 256; off = 294912; }
    else                    { W = W4; K = 128; off = 327680; }
    int N2;
    if (widx < 32768) N2 = 256; else if (widx < 163840) N2 = 512;
    else if (widx < 294912) N2 = 256; else N2 = 128;
    int l = widx - off;
    int nn = l / K, kk = l % K;
    wtbuf[widx] = __float2bfloat16(W[(size_t)kk * N2 + nn]);
}

// ---------------- direct global->LDS 16B staging ----------------

__device__ inline void gl_lds16(const bf16* g, bf16* l) {
    __builtin_amdgcn_global_load_lds(
        (const __attribute__((address_space(1))) void*)g,
        (__attribute__((address_space(3))) void*)l,
        16, 0, 0);
}

// ---------------- MFMA GEMM (64x128 tile): C[M,N] = A[M,K] @ Wt[N,K]^T ----------------
// mode 0: raw store; mode 1: sigmoid(BN(acc+bias)).  Used for N==128 layers (grid parallelism).

template <typename OT>
__global__ __launch_bounds__(256) void mfma_gemm_kernel(
    const bf16* __restrict__ A, const bf16* __restrict__ Wt,
    OT* __restrict__ C, int M, int K, int N, int mode,
    const float* __restrict__ bias, const float* __restrict__ g,
    const float* __restrict__ be, const float* __restrict__ m,
    const float* __restrict__ v) {
    __shared__ bf16 As[64][32];
    __shared__ bf16 Bs[128][32];
    int m0 = blockIdx.x * 64;
    int n0 = blockIdx.y * 128;
    int tid = threadIdx.x;
    int wave = tid >> 6, lane = tid & 63;
    int lrow = lane & 15, quad = lane >> 4;

    f32x4 acc[4][2] = {};   // [m-tile][n-tile]

    int srow = lane >> 2;
    int sseg = lane & 3;
    int am = wave * 16 + srow;
    int bn = wave * 32 + srow;
    bool aok = (m0 + am) < M;

    for (int k0 = 0; k0 < K; k0 += 32) {
        if (aok)
            gl_lds16(A + (size_t)(m0 + am) * K + k0 + sseg * 8, &As[am][sseg * 8]);
        gl_lds16(Wt + (size_t)(n0 + bn) * K + k0 + sseg * 8, &Bs[bn][sseg * 8]);
        gl_lds16(Wt + (size_t)(n0 + bn + 16) * K + k0 + sseg * 8, &Bs[bn + 16][sseg * 8]);
        __syncthreads();

        short8 afrag[4], bfrag[2];
        #pragma unroll
        for (int mt = 0; mt < 4; ++mt)
            afrag[mt] = *(const short8*)(&As[mt * 16 + lrow][quad * 8]);
        #pragma unroll
        for (int nt = 0; nt < 2; ++nt)
            bfrag[nt] = *(const short8*)(&Bs[wave * 32 + nt * 16 + lrow][quad * 8]);
        #pragma unroll
        for (int mt = 0; mt < 4; ++mt)
            #pragma unroll
            for (int nt = 0; nt < 2; ++nt)
                acc[mt][nt] = __builtin_amdgcn_mfma_f32_16x16x32_bf16(
                    afrag[mt], bfrag[nt], acc[mt][nt], 0, 0, 0);
        __syncthreads();
    }
    // C/D: col = lane&15, row = quad*4 + reg
    #pragma unroll
    for (int nt = 0; nt < 2; ++nt) {
        int gn = n0 + wave * 32 + nt * 16 + lrow;
        float bsc = 0.0f, scale = 1.0f, mean = 0.0f, beta = 0.0f;
        if (mode == 1) {
            bsc = bias[gn];
            scale = g[gn] * rsqrtf(v[gn] + BN_EPS);
            mean = m[gn];
            beta = be[gn];
        }
        #pragma unroll
        for (int mt = 0; mt < 4; ++mt) {
            #pragma unroll
            for (int rr = 0; rr < 4; ++rr) {
                int gm = m0 + mt * 16 + quad * 4 + rr;
                if (gm < M) {
                    float a = acc[mt][nt][rr];
                    if (mode == 1) {
                        a = (a + bsc - mean) * scale + beta;
                        a = 1.0f / (1.0f + __expf(-a));
                    }
                    store_val(C, (size_t)gm * N + gn, a);
                }
            }
        }
    }
}

// ---------------- MFMA GEMM (128x128 tile): for N>=256 layers ----------------
// Round 20: halves B re-staging traffic and barriers per output vs 64-row tile;
// wave w computes rows [w*32, w*32+32) x all 128 cols: 16 MFMA per 10 ds_read_b128.

template <typename OT>
__global__ __launch_bounds__(256) void mfma_gemm128_kernel(
    const bf16* __restrict__ A, const bf16* __restrict__ Wt,
    OT* __restrict__ C, int M, int K, int N, int mode,
    const float* __restrict__ bias, const float* __restrict__ g,
    const float* __restrict__ be, const float* __restrict__ m,
    const float* __restrict__ v) {
    __shared__ bf16 As[128][32];
    __shared__ bf16 Bs[128][32];
    int m0 = blockIdx.x * 128;
    int n0 = blockIdx.y * 128;
    int tid = threadIdx.x;
    int wave = tid >> 6, lane = tid & 63;
    int lrow = lane & 15, quad = lane >> 4;

    f32x4 acc[2][8] = {};   // [m-subtile][n-tile]

    int srow = lane >> 2;     // 0..15
    int sseg = lane & 3;      // 16B segment
    int r0 = wave * 16 + srow;            // 0..63
    bool aok0 = (m0 + r0) < M;
    bool aok1 = (m0 + r0 + 64) < M;

    for (int k0 = 0; k0 < K; k0 += 32) {
        if (aok0)
            gl_lds16(A + (size_t)(m0 + r0) * K + k0 + sseg * 8, &As[r0][sseg * 8]);
        if (aok1)
            gl_lds16(A + (size_t)(m0 + r0 + 64) * K + k0 + sseg * 8, &As[r0 + 64][sseg * 8]);
        gl_lds16(Wt + (size_t)(n0 + r0) * K + k0 + sseg * 8, &Bs[r0][sseg * 8]);
        gl_lds16(Wt + (size_t)(n0 + r0 + 64) * K + k0 + sseg * 8, &Bs[r0 + 64][sseg * 8]);
        __syncthreads();

        short8 afrag[2];
        afrag[0] = *(const short8*)(&As[wave * 32 + lrow][quad * 8]);
        afrag[1] = *(const short8*)(&As[wave * 32 + 16 + lrow][quad * 8]);
        #pragma unroll
        for (int nt = 0; nt < 8; ++nt) {
            short8 bfrag = *(const short8*)(&Bs[nt * 16 + lrow][quad * 8]);
            acc[0][nt] = __builtin_amdgcn_mfma_f32_16x16x32_bf16(afrag[0], bfrag, acc[0][nt], 0, 0, 0);
            acc[1][nt] = __builtin_amdgcn_mfma_f32_16x16x32_bf16(afrag[1], bfrag, acc[1][nt], 0, 0, 0);
        }
        __syncthreads();
    }
    // C/D: col = lane&15, row = quad*4 + reg
    #pragma unroll
    for (int nt = 0; nt < 8; ++nt) {
        int gn = n0 + nt * 16 + lrow;
        float bsc = 0.0f, scale = 1.0f, mean = 0.0f, beta = 0.0f;
        if (mode == 1) {
            bsc = bias[gn];
            scale = g[gn] * rsqrtf(v[gn] + BN_EPS);
            mean = m[gn];
            beta = be[gn];
        }
        #pragma unroll
        for (int mt = 0; mt < 2; ++mt) {
            #pragma unroll
            for (int rr = 0; rr < 4; ++rr) {
                int gm = m0 + wave * 32 + mt * 16 + quad * 4 + rr;
                if (gm < M) {
                    float a = acc[mt][nt][rr];
                    if (mode == 1) {
                        a = (a + bsc - mean) * scale + beta;
                        a = 1.0f / (1.0f + __expf(-a));
                    }
                    store_val(C, (size_t)gm * N + gn, a);
                }
            }
        }
    }
}

// ---------------- fp8 aggregation: LDS-staged records + 2-deep pipelined gathers ----------------
// Round-1 structure (known best): coalesced one-row-per-instruction gathers,
// cooperative record staging to a per-wave LDS strip, A/B 8-gather groups (16 in flight).

template <int VEC> struct F8Vec;
template <> struct F8Vec<2> { typedef unsigned short T; };
template <> struct F8Vec<4> { typedef unsigned int T; };

__device__ inline void fma_f8(unsigned short q, float w, float* acc) {
    f32x2 lo = __builtin_amdgcn_cvt_pk_f32_fp8((unsigned int)q, false);
    acc[0] += w * lo.x;
    acc[1] += w * lo.y;
}
__device__ inline void fma_f8(unsigned int q, float w, float* acc) {
    f32x2 lo = __builtin_amdgcn_cvt_pk_f32_fp8(q, false);
    f32x2 hi = __builtin_amdgcn_cvt_pk_f32_fp8(q, true);
    acc[0] += w * lo.x;
    acc[1] += w * lo.y;
    acc[2] += w * hi.x;
    acc[3] += w * hi.y;
}

template <int VEC>
__global__ __launch_bounds__(256) void agg_fp8_kernel(
    const fp8* __restrict__ hw,
    const int* __restrict__ row_ptr, const int2* __restrict__ e8,
    const float* __restrict__ bias,
    const float* __restrict__ g, const float* __restrict__ be,
    const float* __restrict__ m, const float* __restrict__ v,
    bf16* __restrict__ out, int n, int mode) {
    typedef typename F8Vec<VEC>::T T;
    const int dfeat = VEC * 64;
    __shared__ int2 recs[4][64];
    int wave = threadIdx.x >> 6;
    int lane = threadIdx.x & 63;
    int node = blockIdx.x * 4 + wave;
    if (node >= n) return;
    int s = row_ptr[node * NR], e = row_ptr[(node + 1) * NR];
    float acc[VEC];
    #pragma unroll
    for (int i = 0; i < VEC; ++i) acc[i] = 0.0f;
    const unsigned int base = (unsigned int)lane * VEC;

#define LOADG(Q, WV, J0)                                                     \
    _Pragma("unroll")                                                        \
    for (int u = 0; u < 8; ++u) {                                            \
        int2 rec = recs[wave][(J0) + u];                                     \
        WV[u] = __int_as_float(rec.y);                                       \
        Q[u] = *(const T*)(hw + ((unsigned int)rec.x * dfeat + base));       \
    }
#define CONSUME(Q, WV)                                                       \
    _Pragma("unroll")                                                        \
    for (int u = 0; u < 8; ++u) fma_f8(Q[u], WV[u], acc);

    for (int cs = s; cs < e; cs += 64) {
        int cnt = e - cs; if (cnt > 64) cnt = 64;
        // cooperative coalesced record load; pad with {src=0, w=0}
        int2 r0; r0.x = 0; r0.y = 0;
        if (lane < cnt) r0 = e8[cs + lane];
        recs[wave][lane] = r0;
        // wave-local fence: only this wave touches recs[wave][*]
        asm volatile("s_waitcnt vmcnt(0) lgkmcnt(0)" ::: "memory");

        int npad = (cnt + 15) & ~15;   // >= 16
        T qA[8], qB[8];
        float wA[8], wB[8];
        LOADG(qA, wA, 0)
        LOADG(qB, wB, 8)
        for (int j0 = 16; j0 < npad; j0 += 16) {
            CONSUME(qA, wA)            // waits vmcnt(8): B still in flight
            LOADG(qA, wA, j0)
            CONSUME(qB, wB)
            LOADG(qB, wB, j0 + 8)
        }
        CONSUME(qA, wA)
        CONSUME(qB, wB)
    }
#undef LOADG
#undef CONSUME

    #pragma unroll
    for (int i = 0; i < VEC; ++i) {
        int f = (int)base + i;
        float a = acc[i];
        if (mode != 0) {
            a += bias[f];
            if (mode == 1) {
                float scale = g[f] * rsqrtf(v[f] + BN_EPS);
                a = (a - m[f]) * scale + be[f];
            }
            a = 1.0f / (1.0f + __expf(-a));
        }
        out[(size_t)node * dfeat + f] = __float2bfloat16(a);
    }
}

// ---------------- final h^T h via MFMA ----------------
#define TPAD 8

__global__ __launch_bounds__(256) void htht_mfma_kernel(
    const bf16* __restrict__ h, float* __restrict__ partial, int n) {
    __shared__ bf16 hsT[128][32 + TPAD];
    int b = blockIdx.x;
    int tid = threadIdx.x;
    int wave = tid >> 6, lane = tid & 63;
    int lrow = lane & 15, quad = lane >> 4;

    f32x4 acc[2][8] = {};

    int kk = tid >> 3;
    int seg = tid & 7;

    for (int kt = 0; kt < 8; ++kt) {
        int k0 = b * 256 + kt * 32;
        #pragma unroll
        for (int s2 = 0; s2 < 2; ++s2) {
            int fs = (seg + s2 * 8) * 8;
            int gk = k0 + kk;
            uint4 q; q.x = q.y = q.z = q.w = 0u;
            if (gk < n) q = *(const uint4*)(h + (size_t)gk * 128 + fs);
            const unsigned short* u = (const unsigned short*)&q;
            #pragma unroll
            for (int i = 0; i < 8; ++i)
                *((unsigned short*)&hsT[fs + i][kk]) = u[i];
        }
        __syncthreads();
        short8 af0 = *(const short8*)(&hsT[wave * 32 + lrow][quad * 8]);
        short8 af1 = *(const short8*)(&hsT[wave * 32 + 16 + lrow][quad * 8]);
        #pragma unroll
        for (int t = 0; t < 8; ++t) {
            short8 bfrag = *(const short8*)(&hsT[t * 16 + lrow][quad * 8]);
            acc[0][t] = __builtin_amdgcn_mfma_f32_16x16x32_bf16(af0, bfrag, acc[0][t], 0, 0, 0);
            acc[1][t] = __builtin_amdgcn_mfma_f32_16x16x32_bf16(af1, bfrag, acc[1][t], 0, 0, 0);
        }
        __syncthreads();
    }
    float* p = partial + (size_t)b * 16384;
    #pragma unroll
    for (int a_ = 0; a_ < 2; ++a_) {
        #pragma unroll
        for (int t = 0; t < 8; ++t) {
            #pragma unroll
            for (int rr = 0; rr < 4; ++rr) {
                int gm = wave * 32 + a_ * 16 + quad * 4 + rr;
                int gn = t * 16 + lrow;
                p[gm * 128 + gn] = acc[a_][t][rr];
            }
        }
    }
}

__global__ void reduce_kernel(const float* __restrict__ partial, float* __restrict__ out, int nchunks) {
    int idx = blockIdx.x * blockDim.x + threadIdx.x;
    float s = 0.0f;
    for (int c = 0; c < nchunks; ++c) s += partial[(size_t)c * 16384 + idx];
    int i = idx / 128, j = idx % 128;
    out[idx] = (i == j) ? 0.0f : s;
}

// ---------------- launch ----------------
extern "C" void kernel_launch(void* const* d_in, const int* in_sizes, int n_in,
                              void* d_out, int out_size, void* d_ws, size_t ws_size,
                              hipStream_t stream) {
    const float* x  = (const float*)d_in[0];
    const int*   ei = (const int*)d_in[1];
    const float* ea = (const float*)d_in[2];
    const float* W[5];  const float* bvec[5];
    for (int l = 0; l < 5; ++l) { W[l] = (const float*)d_in[3 + 2 * l]; bvec[l] = (const float*)d_in[4 + 2 * l]; }
    const float* g[4]; const float* be[4]; const float* mm[4]; const float* vv[4];
    for (int l = 0; l < 4; ++l) {
        g[l]  = (const float*)d_in[13 + 4 * l];
        be[l] = (const float*)d_in[14 + 4 * l];
        mm[l] = (const float*)d_in[15 + 4 * l];
        vv[l] = (const float*)d_in[16 + 4 * l];
    }
    const int n = in_sizes[0] / NSF;        // 20000
    const int E = in_sizes[1] / 2;          // 500000
    const int EN = E + n;
    const int rsize = (n + NR - 1) / NR;
    const int total = n * NR;
    const int nscan = (total + SCK - 1) / SCK;
    const int dims[6] = {128, 256, 512, 256, 128, 128};
    const int wtoff[5] = {0, 32768, 163840, 294912, 327680};
    const int wtelems = 344064;

    // workspace layout (256B aligned); ~69 MB
    auto align = [](size_t o) { return (o + 255) & ~(size_t)255; };
    size_t off = 0;
    float* dinv    = (float*)((char*)d_ws + off); off = align(off + (size_t)n * 4);
    int*   fill    = (int*)  ((char*)d_ws + off); off = align(off + (size_t)total * 4);
    int*   row_ptr = (int*)  ((char*)d_ws + off); off = align(off + ((size_t)total + 1) * 4);
    int*   blksum  = (int*)  ((char*)d_ws + off); off = align(off + (size_t)256 * 4);
    int*   locb    = (int*)  ((char*)d_ws + off); off = align(off + (size_t)EN * 4);
    int2*  e8      = (int2*) ((char*)d_ws + off); off = align(off + (size_t)EN * 8);
    int*   csr_col = (int*)  ((char*)d_ws + off); off = align(off + (size_t)EN * 4);
    bf16*  wtbuf   = (bf16*) ((char*)d_ws + off); off = align(off + (size_t)wtelems * 2);
    fp8*   xq      = (fp8*)  ((char*)d_ws + off); off = align(off + (size_t)n * 128);
    bf16*  hbuf    = (bf16*) ((char*)d_ws + off); off = align(off + (size_t)n * 512 * 2);
    bf16*  abuf    = (bf16*) ((char*)d_ws + off); off = align(off + (size_t)n * 512 * 2);
    fp8*   f8buf   = (fp8*)  ((char*)d_ws + off); off = align(off + (size_t)n * 256);
    const int KCH = (20000 + 255) / 256;    // 79
    float* partial = (float*)((char*)d_ws + off); off = align(off + (size_t)KCH * 16384 * 4);

    // fused prep: zero fill + x->fp8 + W->Wt (one launch, independent of edges)
    {
        int xcnt = n * 128;
        int items = total + xcnt + wtelems;
        prep_kernel<<<(items + 255) / 256, 256, 0, stream>>>(fill, total, x, xq, xcnt,
            W[0], W[1], W[2], W[3], W[4], wtbuf, wtelems);
    }

    // CSR build (1 atomic/edge, packed edge records)
    passA_kernel<<<(EN + 255) / 256, 256, 0, stream>>>(ei, fill, locb, E, n, rsize);
    scan1_kernel<<<nscan, 256, 0, stream>>>(fill, blksum, total);
    scan2_kernel<<<1, 256, 0, stream>>>(blksum, row_ptr, nscan, total);
    scan3_kernel<<<nscan, 256, 0, stream>>>(fill, blksum, row_ptr, total);
    passB_kernel<<<(EN + 255) / 256, 256, 0, stream>>>(ei, ea, row_ptr, locb,
                                                       e8, csr_col, E, n, rsize);
    degdinv_kernel<<<(n + 255) / 256, 256, 0, stream>>>(row_ptr, e8, dinv, n);
    normw_kernel<<<(EN + 255) / 256, 256, 0, stream>>>(dinv, csr_col, e8, EN);

    int ablocks = (n + 3) / 4;
    auto gemm_bf16 = [&](const bf16* A, int l, bf16* C, int mode) {
        int K = dims[l], N = dims[l + 1];
        int bi = (l < 4) ? l : 0;
        if (N >= 256) {
            dim3 gg((n + 127) / 128, N / 128);
            mfma_gemm128_kernel<bf16><<<gg, 256, 0, stream>>>(A, wtbuf + wtoff[l], C, n, K, N, mode,
                                                              bvec[l], g[bi], be[bi], mm[bi], vv[bi]);
        } else {
            dim3 gg((n + 63) / 64, N / 128);
            mfma_gemm_kernel<bf16><<<gg, 256, 0, stream>>>(A, wtbuf + wtoff[l], C, n, K, N, mode,
                                                           bvec[l], g[bi], be[bi], mm[bi], vv[bi]);
        }
    };
    auto gemm_fp8 = [&](const bf16* A, int l, fp8* C, int mode) {
        int K = dims[l], N = dims[l + 1];
        int bi = (l < 4) ? l : 0;
        if (N >= 256) {
            dim3 gg((n + 127) / 128, N / 128);
            mfma_gemm128_kernel<fp8><<<gg, 256, 0, stream>>>(A, wtbuf + wtoff[l], C, n, K, N, mode,
                                                             bvec[l], g[bi], be[bi], mm[bi], vv[bi]);
        } else {
            dim3 gg((n + 63) / 64, N / 128);
            mfma_gemm_kernel<fp8><<<gg, 256, 0, stream>>>(A, wtbuf + wtoff[l], C, n, K, N, mode,
                                                          bvec[l], g[bi], be[bi], mm[bi], vv[bi]);
        }
    };

    // L1 (128->256): agg-first fp8 128 (xq), GEMM1 fused act -> fp8 h1
    agg_fp8_kernel<2><<<ablocks, 256, 0, stream>>>(xq, row_ptr, e8,
        bvec[0], bvec[0], bvec[0], bvec[0], bvec[0], abuf, n, 0);
    gemm_fp8(abuf, 0, f8buf, 1);
    // L2 (256->512): agg-first fp8 256 (h1) -> bf16, GEMM2 fused act -> bf16 h2 (512)
    agg_fp8_kernel<4><<<ablocks, 256, 0, stream>>>(f8buf, row_ptr, e8,
        bvec[1], bvec[1], bvec[1], bvec[1], bvec[1], abuf, n, 0);
    gemm_bf16(abuf, 1, hbuf, 1);
    // L3 (512->256): GEMM3 raw -> fp8 hw3, agg-last fp8 256 + bias+BN+sigmoid -> bf16 h3
    gemm_fp8(hbuf, 2, f8buf, 0);
    agg_fp8_kernel<4><<<ablocks, 256, 0, stream>>>(f8buf, row_ptr, e8,
        bvec[2], g[2], be[2], mm[2], vv[2], abuf, n, 1);
    // L4 (256->128): GEMM4 raw -> fp8 hw4, agg-last fp8 128 + bias+BN+sigmoid -> bf16 h4
    gemm_fp8(abuf, 3, f8buf, 0);
    agg_fp8_kernel<2><<<ablocks, 256, 0, stream>>>(f8buf, row_ptr, e8,
        bvec[3], g[3], be[3], mm[3], vv[3], hbuf, n, 1);
    // L5 (128->128): GEMM5 raw -> fp8 hw5, agg-last fp8 128 + bias+sigmoid -> bf16 h5
    gemm_fp8(hbuf, 4, f8buf, 0);
    agg_fp8_kernel<2><<<ablocks, 256, 0, stream>>>(f8buf, row_ptr, e8,
        bvec[4], bvec[4], bvec[4], bvec[4], bvec[4], abuf, n, 2);

    // final h^T h with zeroed diagonal (MFMA)
    htht_mfma_kernel<<<KCH, 256, 0, stream>>>(abuf, partial, n);
    reduce_kernel<<<16384 / 256, 256, 0, stream>>>(partial, (float*)d_out, KCH);
}

// Round 8
// 375.559 us; speedup vs baseline: 1.2097x; 1.0498x over previous
//
#include <hip/hip_runtime.h>
#include <hip/hip_bf16.h>
#include <hip/hip_fp8.h>
#include <cstdint>
#include <cstddef>
#include <cstring>

typedef __hip_bfloat16 bf16;
typedef unsigned char fp8;                                  // e4m3 storage
typedef __attribute__((ext_vector_type(8))) short short8;   // 8 bf16 (MFMA A/B frag)
typedef __attribute__((ext_vector_type(4))) float f32x4;    // MFMA C/D frag
typedef __attribute__((ext_vector_type(2))) float f32x2;

#define NSF 128
#define BN_EPS 1e-3f
#define NR 4            // src ranges per node
#define SCK 2048        // elements per scan block

// ---------------- CSR build: 1 atomic per edge ----------------

__global__ void passA_kernel(const int* __restrict__ ei, int* __restrict__ fill,
                             int* __restrict__ loc, int E, int n, int rsize) {
    int idx = blockIdx.x * blockDim.x + threadIdx.x;
    if (idx < E) {
        int r = ei[idx];
        int c = ei[E + idx];
        int slot = c * NR + r / rsize;
        loc[idx] = atomicAdd(&fill[slot], 1);
    } else if (idx < E + n) {
        int i = idx - E;
        int slot = i * NR + i / rsize;
        loc[idx] = atomicAdd(&fill[slot], 1);
    }
}

// ---- hierarchical exclusive scan of fill -> row_ptr ----

__global__ void scan1_kernel(const int* __restrict__ cnt, int* __restrict__ blksum, int total) {
    __shared__ int red[256];
    int base = blockIdx.x * SCK + threadIdx.x * 8;
    int s = 0;
    #pragma unroll
    for (int i = 0; i < 8; ++i) {
        int idx = base + i;
        if (idx < total) s += cnt[idx];
    }
    red[threadIdx.x] = s;
    __syncthreads();
    for (int off2 = 128; off2 > 0; off2 >>= 1) {
        if (threadIdx.x < off2) red[threadIdx.x] += red[threadIdx.x + off2];
        __syncthreads();
    }
    if (threadIdx.x == 0) blksum[blockIdx.x] = red[0];
}

__global__ void scan2_kernel(int* __restrict__ blksum, int* __restrict__ row_ptr,
                             int nblk, int total) {
    __shared__ int part[256];
    int tid = threadIdx.x;
    int v = (tid < nblk) ? blksum[tid] : 0;
    part[tid] = v;
    __syncthreads();
    for (int off2 = 1; off2 < 256; off2 <<= 1) {
        int t = (tid >= off2) ? part[tid - off2] : 0;
        __syncthreads();
        part[tid] += t;
        __syncthreads();
    }
    if (tid < nblk) blksum[tid] = part[tid] - v;
    if (tid == 255) row_ptr[total] = part[255];
}

__global__ void scan3_kernel(const int* __restrict__ cnt, const int* __restrict__ blkoff,
                             int* __restrict__ row_ptr, int total) {
    __shared__ int part[256];
    int tid = threadIdx.x;
    int base = blockIdx.x * SCK + tid * 8;
    int loc[8]; int s = 0;
    #pragma unroll
    for (int i = 0; i < 8; ++i) {
        int idx = base + i;
        loc[i] = (idx < total) ? cnt[idx] : 0;
        s += loc[i];
    }
    part[tid] = s;
    __syncthreads();
    for (int off2 = 1; off2 < 256; off2 <<= 1) {
        int t = (tid >= off2) ? part[tid - off2] : 0;
        __syncthreads();
        part[tid] += t;
        __syncthreads();
    }
    int run = blkoff[blockIdx.x] + part[tid] - s;
    #pragma unroll
    for (int i = 0; i < 8; ++i) {
        int idx = base + i;
        if (idx < total) { row_ptr[idx] = run; run += loc[i]; }
    }
}

// passB: scatter without atomics; packed edge record {src, w_bits}
__global__ void passB_kernel(const int* __restrict__ ei, const float* __restrict__ ea,
                             const int* __restrict__ row_ptr, const int* __restrict__ loc,
                             int2* __restrict__ e8, int* __restrict__ csr_col,
                             int E, int n, int rsize) {
    int idx = blockIdx.x * blockDim.x + threadIdx.x;
    if (idx < E) {
        int r = ei[idx];
        int c = ei[E + idx];
        int slot = c * NR + r / rsize;
        int p = row_ptr[slot] + loc[idx];
        int2 rec; rec.x = r; rec.y = __float_as_int(ea[idx]);
        e8[p] = rec;
        csr_col[p] = c;
    } else if (idx < E + n) {
        int i = idx - E;
        int slot = i * NR + i / rsize;
        int p = row_ptr[slot] + loc[idx];
        int2 rec; rec.x = i; rec.y = __float_as_int(1.0f);
        e8[p] = rec;
        csr_col[p] = i;
    }
}

__global__ void degdinv_kernel(const int* __restrict__ row_ptr, const int2* __restrict__ e8,
                               float* __restrict__ dinv, int n) {
    int node = blockIdx.x * blockDim.x + threadIdx.x;
    if (node < n) {
        int s = row_ptr[node * NR], e = row_ptr[(node + 1) * NR];
        float d = 0.0f;
        for (int j = s; j < e; ++j) d += __int_as_float(e8[j].y);
        dinv[node] = (d > 0.0f) ? rsqrtf(d) : 0.0f;
    }
}

__global__ void normw_kernel(const float* __restrict__ dinv, const int* __restrict__ csr_col,
                             int2* __restrict__ e8, int EN) {
    int p = blockIdx.x * blockDim.x + threadIdx.x;
    if (p < EN) {
        int2 rec = e8[p];
        float w = dinv[rec.x] * __int_as_float(rec.y) * dinv[csr_col[p]];
        ((int*)e8)[2 * p + 1] = __float_as_int(w);
    }
}

// ---------------- output-type helpers (HW fp8 cvt) ----------------

__device__ inline void store_val(bf16* C, size_t idx, float a) {
    C[idx] = __float2bfloat16(a);
}
__device__ inline void store_val(fp8* C, size_t idx, float a) {
    int packed = __builtin_amdgcn_cvt_pk_fp8_f32(a, a, 0, false);
    C[idx] = (fp8)(packed & 0xff);
}

// ---------------- fused prep: zero fill[] + x->fp8 + all W->Wt(bf16), one launch ----------------
__global__ void prep_kernel(int* __restrict__ fill, int total,
                            const float* __restrict__ x, fp8* __restrict__ xq, int xcnt,
                            const float* __restrict__ W0, const float* __restrict__ W1,
                            const float* __restrict__ W2, const float* __restrict__ W3,
                            const float* __restrict__ W4,
                            bf16* __restrict__ wtbuf, int wtelems) {
    int idx = blockIdx.x * blockDim.x + threadIdx.x;
    if (idx < total) { fill[idx] = 0; return; }
    idx -= total;
    if (idx < xcnt) {
        store_val(xq, idx, x[idx]);
        return;
    }
    int widx = idx - xcnt;
    if (widx >= wtelems) return;
    // layer boundaries (cumulative K*N): 32768, 163840, 294912, 327680, 344064
    const float* W; int K, off;
    if (widx < 32768)       { W = W0; K = 128; off = 0; }
    else if (widx < 163840) { W = W1; K = 256; off = 32768; }
    else if (widx < 294912) { W = W2; K = 512; off = 163840; }
    else if (widx < 327680) { W = W3; K = 256; off = 294912; }
    else                    { W = W4; K = 128; off = 327680; }
    int N2;
    if (widx < 32768) N2 = 256; else if (widx < 163840) N2 = 512;
    else if (widx < 294912) N2 = 256; else N2 = 128;
    int l = widx - off;
    int nn = l / K, kk = l % K;
    wtbuf[widx] = __float2bfloat16(W[(size_t)kk * N2 + nn]);
}

// ---------------- direct global->LDS 16B staging ----------------

__device__ inline void gl_lds16(const bf16* g, bf16* l) {
    __builtin_amdgcn_global_load_lds(
        (const __attribute__((address_space(1))) void*)g,
        (__attribute__((address_space(3))) void*)l,
        16, 0, 0);
}

// ---------------- MFMA GEMM (64x128 tile, BK=64 dual-stage): C = A @ Wt^T ----------------
// Round 23: two 32-K slabs staged into separate LDS buffers back-to-back (6 gl_lds in
// flight), then one barrier pair covers 16 MFMAs/wave (was 8). Halves barrier drains.
// mode 0: raw store; mode 1: sigmoid(BN(acc+bias))

template <typename OT>
__global__ __launch_bounds__(256) void mfma_gemm_kernel(
    const bf16* __restrict__ A, const bf16* __restrict__ Wt,
    OT* __restrict__ C, int M, int K, int N, int mode,
    const float* __restrict__ bias, const float* __restrict__ g,
    const float* __restrict__ be, const float* __restrict__ m,
    const float* __restrict__ v) {
    __shared__ bf16 As[2][64][32];
    __shared__ bf16 Bs[2][128][32];
    int m0 = blockIdx.x * 64;
    int n0 = blockIdx.y * 128;
    int tid = threadIdx.x;
    int wave = tid >> 6, lane = tid & 63;
    int lrow = lane & 15, quad = lane >> 4;

    f32x4 acc[4][2] = {};   // [m-tile][n-tile]

    int srow = lane >> 2;
    int sseg = lane & 3;
    int am = wave * 16 + srow;
    int bn = wave * 32 + srow;
    bool aok = (m0 + am) < M;

    for (int k0 = 0; k0 < K; k0 += 64) {
        if (aok) {
            gl_lds16(A + (size_t)(m0 + am) * K + k0 + sseg * 8,      &As[0][am][sseg * 8]);
            gl_lds16(A + (size_t)(m0 + am) * K + k0 + 32 + sseg * 8, &As[1][am][sseg * 8]);
        }
        gl_lds16(Wt + (size_t)(n0 + bn) * K + k0 + sseg * 8,           &Bs[0][bn][sseg * 8]);
        gl_lds16(Wt + (size_t)(n0 + bn) * K + k0 + 32 + sseg * 8,      &Bs[1][bn][sseg * 8]);
        gl_lds16(Wt + (size_t)(n0 + bn + 16) * K + k0 + sseg * 8,      &Bs[0][bn + 16][sseg * 8]);
        gl_lds16(Wt + (size_t)(n0 + bn + 16) * K + k0 + 32 + sseg * 8, &Bs[1][bn + 16][sseg * 8]);
        __syncthreads();

        #pragma unroll
        for (int ks = 0; ks < 2; ++ks) {
            short8 afrag[4], bfrag[2];
            #pragma unroll
            for (int mt = 0; mt < 4; ++mt)
                afrag[mt] = *(const short8*)(&As[ks][mt * 16 + lrow][quad * 8]);
            #pragma unroll
            for (int nt = 0; nt < 2; ++nt)
                bfrag[nt] = *(const short8*)(&Bs[ks][wave * 32 + nt * 16 + lrow][quad * 8]);
            #pragma unroll
            for (int mt = 0; mt < 4; ++mt)
                #pragma unroll
                for (int nt = 0; nt < 2; ++nt)
                    acc[mt][nt] = __builtin_amdgcn_mfma_f32_16x16x32_bf16(
                        afrag[mt], bfrag[nt], acc[mt][nt], 0, 0, 0);
        }
        __syncthreads();
    }
    // C/D: col = lane&15, row = quad*4 + reg
    #pragma unroll
    for (int nt = 0; nt < 2; ++nt) {
        int gn = n0 + wave * 32 + nt * 16 + lrow;
        float bsc = 0.0f, scale = 1.0f, mean = 0.0f, beta = 0.0f;
        if (mode == 1) {
            bsc = bias[gn];
            scale = g[gn] * rsqrtf(v[gn] + BN_EPS);
            mean = m[gn];
            beta = be[gn];
        }
        #pragma unroll
        for (int mt = 0; mt < 4; ++mt) {
            #pragma unroll
            for (int rr = 0; rr < 4; ++rr) {
                int gm = m0 + mt * 16 + quad * 4 + rr;
                if (gm < M) {
                    float a = acc[mt][nt][rr];
                    if (mode == 1) {
                        a = (a + bsc - mean) * scale + beta;
                        a = 1.0f / (1.0f + __expf(-a));
                    }
                    store_val(C, (size_t)gm * N + gn, a);
                }
            }
        }
    }
}

// ---------------- fp8 aggregation: LDS-staged records + 2-deep pipelined gathers ----------------
// Round-1 structure (known best): coalesced one-row-per-instruction gathers,
// cooperative record staging to a per-wave LDS strip, A/B 8-gather groups (16 in flight).

template <int VEC> struct F8Vec;
template <> struct F8Vec<2> { typedef unsigned short T; };
template <> struct F8Vec<4> { typedef unsigned int T; };

__device__ inline void fma_f8(unsigned short q, float w, float* acc) {
    f32x2 lo = __builtin_amdgcn_cvt_pk_f32_fp8((unsigned int)q, false);
    acc[0] += w * lo.x;
    acc[1] += w * lo.y;
}
__device__ inline void fma_f8(unsigned int q, float w, float* acc) {
    f32x2 lo = __builtin_amdgcn_cvt_pk_f32_fp8(q, false);
    f32x2 hi = __builtin_amdgcn_cvt_pk_f32_fp8(q, true);
    acc[0] += w * lo.x;
    acc[1] += w * lo.y;
    acc[2] += w * hi.x;
    acc[3] += w * hi.y;
}

template <int VEC>
__global__ __launch_bounds__(256) void agg_fp8_kernel(
    const fp8* __restrict__ hw,
    const int* __restrict__ row_ptr, const int2* __restrict__ e8,
    const float* __restrict__ bias,
    const float* __restrict__ g, const float* __restrict__ be,
    const float* __restrict__ m, const float* __restrict__ v,
    bf16* __restrict__ out, int n, int mode) {
    typedef typename F8Vec<VEC>::T T;
    const int dfeat = VEC * 64;
    __shared__ int2 recs[4][64];
    int wave = threadIdx.x >> 6;
    int lane = threadIdx.x & 63;
    int node = blockIdx.x * 4 + wave;
    if (node >= n) return;
    int s = row_ptr[node * NR], e = row_ptr[(node + 1) * NR];
    float acc[VEC];
    #pragma unroll
    for (int i = 0; i < VEC; ++i) acc[i] = 0.0f;
    const unsigned int base = (unsigned int)lane * VEC;

#define LOADG(Q, WV, J0)                                                     \
    _Pragma("unroll")                                                        \
    for (int u = 0; u < 8; ++u) {                                            \
        int2 rec = recs[wave][(J0) + u];                                     \
        WV[u] = __int_as_float(rec.y);                                       \
        Q[u] = *(const T*)(hw + ((unsigned int)rec.x * dfeat + base));       \
    }
#define CONSUME(Q, WV)                                                       \
    _Pragma("unroll")                                                        \
    for (int u = 0; u < 8; ++u) fma_f8(Q[u], WV[u], acc);

    for (int cs = s; cs < e; cs += 64) {
        int cnt = e - cs; if (cnt > 64) cnt = 64;
        // cooperative coalesced record load; pad with {src=0, w=0}
        int2 r0; r0.x = 0; r0.y = 0;
        if (lane < cnt) r0 = e8[cs + lane];
        recs[wave][lane] = r0;
        // wave-local fence: only this wave touches recs[wave][*]
        asm volatile("s_waitcnt vmcnt(0) lgkmcnt(0)" ::: "memory");

        int npad = (cnt + 15) & ~15;   // >= 16
        T qA[8], qB[8];
        float wA[8], wB[8];
        LOADG(qA, wA, 0)
        LOADG(qB, wB, 8)
        for (int j0 = 16; j0 < npad; j0 += 16) {
            CONSUME(qA, wA)            // waits vmcnt(8): B still in flight
            LOADG(qA, wA, j0)
            CONSUME(qB, wB)
            LOADG(qB, wB, j0 + 8)
        }
        CONSUME(qA, wA)
        CONSUME(qB, wB)
    }
#undef LOADG
#undef CONSUME

    #pragma unroll
    for (int i = 0; i < VEC; ++i) {
        int f = (int)base + i;
        float a = acc[i];
        if (mode != 0) {
            a += bias[f];
            if (mode == 1) {
                float scale = g[f] * rsqrtf(v[f] + BN_EPS);
                a = (a - m[f]) * scale + be[f];
            }
            a = 1.0f / (1.0f + __expf(-a));
        }
        out[(size_t)node * dfeat + f] = __float2bfloat16(a);
    }
}

// ---------------- final h^T h via MFMA ----------------
#define TPAD 8

__global__ __launch_bounds__(256) void htht_mfma_kernel(
    const bf16* __restrict__ h, float* __restrict__ partial, int n) {
    __shared__ bf16 hsT[128][32 + TPAD];
    int b = blockIdx.x;
    int tid = threadIdx.x;
    int wave = tid >> 6, lane = tid & 63;
    int lrow = lane & 15, quad = lane >> 4;

    f32x4 acc[2][8] = {};

    int kk = tid >> 3;
    int seg = tid & 7;

    for (int kt = 0; kt < 8; ++kt) {
        int k0 = b * 256 + kt * 32;
        #pragma unroll
        for (int s2 = 0; s2 < 2; ++s2) {
            int fs = (seg + s2 * 8) * 8;
            int gk = k0 + kk;
            uint4 q; q.x = q.y = q.z = q.w = 0u;
            if (gk < n) q = *(const uint4*)(h + (size_t)gk * 128 + fs);
            const unsigned short* u = (const unsigned short*)&q;
            #pragma unroll
            for (int i = 0; i < 8; ++i)
                *((unsigned short*)&hsT[fs + i][kk]) = u[i];
        }
        __syncthreads();
        short8 af0 = *(const short8*)(&hsT[wave * 32 + lrow][quad * 8]);
        short8 af1 = *(const short8*)(&hsT[wave * 32 + 16 + lrow][quad * 8]);
        #pragma unroll
        for (int t = 0; t < 8; ++t) {
            short8 bfrag = *(const short8*)(&hsT[t * 16 + lrow][quad * 8]);
            acc[0][t] = __builtin_amdgcn_mfma_f32_16x16x32_bf16(af0, bfrag, acc[0][t], 0, 0, 0);
            acc[1][t] = __builtin_amdgcn_mfma_f32_16x16x32_bf16(af1, bfrag, acc[1][t], 0, 0, 0);
        }
        __syncthreads();
    }
    float* p = partial + (size_t)b * 16384;
    #pragma unroll
    for (int a_ = 0; a_ < 2; ++a_) {
        #pragma unroll
        for (int t = 0; t < 8; ++t) {
            #pragma unroll
            for (int rr = 0; rr < 4; ++rr) {
                int gm = wave * 32 + a_ * 16 + quad * 4 + rr;
                int gn = t * 16 + lrow;
                p[gm * 128 + gn] = acc[a_][t][rr];
            }
        }
    }
}

__global__ void reduce_kernel(const float* __restrict__ partial, float* __restrict__ out, int nchunks) {
    int idx = blockIdx.x * blockDim.x + threadIdx.x;
    float s = 0.0f;
    for (int c = 0; c < nchunks; ++c) s += partial[(size_t)c * 16384 + idx];
    int i = idx / 128, j = idx % 128;
    out[idx] = (i == j) ? 0.0f : s;
}

// ---------------- launch ----------------
extern "C" void kernel_launch(void* const* d_in, const int* in_sizes, int n_in,
                              void* d_out, int out_size, void* d_ws, size_t ws_size,
                              hipStream_t stream) {
    const float* x  = (const float*)d_in[0];
    const int*   ei = (const int*)d_in[1];
    const float* ea = (const float*)d_in[2];
    const float* W[5];  const float* bvec[5];
    for (int l = 0; l < 5; ++l) { W[l] = (const float*)d_in[3 + 2 * l]; bvec[l] = (const float*)d_in[4 + 2 * l]; }
    const float* g[4]; const float* be[4]; const float* mm[4]; const float* vv[4];
    for (int l = 0; l < 4; ++l) {
        g[l]  = (const float*)d_in[13 + 4 * l];
        be[l] = (const float*)d_in[14 + 4 * l];
        mm[l] = (const float*)d_in[15 + 4 * l];
        vv[l] = (const float*)d_in[16 + 4 * l];
    }
    const int n = in_sizes[0] / NSF;        // 20000
    const int E = in_sizes[1] / 2;          // 500000
    const int EN = E + n;
    const int rsize = (n + NR - 1) / NR;
    const int total = n * NR;
    const int nscan = (total + SCK - 1) / SCK;
    const int dims[6] = {128, 256, 512, 256, 128, 128};
    const int wtoff[5] = {0, 32768, 163840, 294912, 327680};
    const int wtelems = 344064;

    // workspace layout (256B aligned); ~69 MB (identical to known-good round-1 layout)
    auto align = [](size_t o) { return (o + 255) & ~(size_t)255; };
    size_t off = 0;
    float* dinv    = (float*)((char*)d_ws + off); off = align(off + (size_t)n * 4);
    int*   fill    = (int*)  ((char*)d_ws + off); off = align(off + (size_t)total * 4);
    int*   row_ptr = (int*)  ((char*)d_ws + off); off = align(off + ((size_t)total + 1) * 4);
    int*   blksum  = (int*)  ((char*)d_ws + off); off = align(off + (size_t)256 * 4);
    int*   locb    = (int*)  ((char*)d_ws + off); off = align(off + (size_t)EN * 4);
    int2*  e8      = (int2*) ((char*)d_ws + off); off = align(off + (size_t)EN * 8);
    int*   csr_col = (int*)  ((char*)d_ws + off); off = align(off + (size_t)EN * 4);
    bf16*  wtbuf   = (bf16*) ((char*)d_ws + off); off = align(off + (size_t)wtelems * 2);
    fp8*   xq      = (fp8*)  ((char*)d_ws + off); off = align(off + (size_t)n * 128);
    bf16*  hbuf    = (bf16*) ((char*)d_ws + off); off = align(off + (size_t)n * 512 * 2);
    bf16*  abuf    = (bf16*) ((char*)d_ws + off); off = align(off + (size_t)n * 512 * 2);
    fp8*   f8buf   = (fp8*)  ((char*)d_ws + off); off = align(off + (size_t)n * 256);
    const int KCH = (20000 + 255) / 256;    // 79
    float* partial = (float*)((char*)d_ws + off); off = align(off + (size_t)KCH * 16384 * 4);

    // fused prep: zero fill + x->fp8 + W->Wt (one launch, independent of edges)
    {
        int xcnt = n * 128;
        int items = total + xcnt + wtelems;
        prep_kernel<<<(items + 255) / 256, 256, 0, stream>>>(fill, total, x, xq, xcnt,
            W[0], W[1], W[2], W[3], W[4], wtbuf, wtelems);
    }

    // CSR build (1 atomic/edge, packed edge records)
    passA_kernel<<<(EN + 255) / 256, 256, 0, stream>>>(ei, fill, locb, E, n, rsize);
    scan1_kernel<<<nscan, 256, 0, stream>>>(fill, blksum, total);
    scan2_kernel<<<1, 256, 0, stream>>>(blksum, row_ptr, nscan, total);
    scan3_kernel<<<nscan, 256, 0, stream>>>(fill, blksum, row_ptr, total);
    passB_kernel<<<(EN + 255) / 256, 256, 0, stream>>>(ei, ea, row_ptr, locb,
                                                       e8, csr_col, E, n, rsize);
    degdinv_kernel<<<(n + 255) / 256, 256, 0, stream>>>(row_ptr, e8, dinv, n);
    normw_kernel<<<(EN + 255) / 256, 256, 0, stream>>>(dinv, csr_col, e8, EN);

    int ablocks = (n + 3) / 4;
    auto gemm_bf16 = [&](const bf16* A, int l, bf16* C, int mode) {
        int K = dims[l], N = dims[l + 1];
        dim3 gg((n + 63) / 64, N / 128);
        int bi = (l < 4) ? l : 0;
        mfma_gemm_kernel<bf16><<<gg, 256, 0, stream>>>(A, wtbuf + wtoff[l], C, n, K, N, mode,
                                                       bvec[l], g[bi], be[bi], mm[bi], vv[bi]);
    };
    auto gemm_fp8 = [&](const bf16* A, int l, fp8* C, int mode) {
        int K = dims[l], N = dims[l + 1];
        dim3 gg((n + 63) / 64, N / 128);
        int bi = (l < 4) ? l : 0;
        mfma_gemm_kernel<fp8><<<gg, 256, 0, stream>>>(A, wtbuf + wtoff[l], C, n, K, N, mode,
                                                      bvec[l], g[bi], be[bi], mm[bi], vv[bi]);
    };

    // L1 (128->256): agg-first fp8 128 (xq), GEMM1 fused act -> fp8 h1
    agg_fp8_kernel<2><<<ablocks, 256, 0, stream>>>(xq, row_ptr, e8,
        bvec[0], bvec[0], bvec[0], bvec[0], bvec[0], abuf, n, 0);
    gemm_fp8(abuf, 0, f8buf, 1);
    // L2 (256->512): agg-first fp8 256 (h1) -> bf16, GEMM2 fused act -> bf16 h2 (512)
    agg_fp8_kernel<4><<<ablocks, 256, 0, stream>>>(f8buf, row_ptr, e8,
        bvec[1], bvec[1], bvec[1], bvec[1], bvec[1], abuf, n, 0);
    gemm_bf16(abuf, 1, hbuf, 1);
    // L3 (512->256): GEMM3 raw -> fp8 hw3, agg-last fp8 256 + bias+BN+sigmoid -> bf16 h3
    gemm_fp8(hbuf, 2, f8buf, 0);
    agg_fp8_kernel<4><<<ablocks, 256, 0, stream>>>(f8buf, row_ptr, e8,
        bvec[2], g[2], be[2], mm[2], vv[2], abuf, n, 1);
    // L4 (256->128): GEMM4 raw -> fp8 hw4, agg-last fp8 128 + bias+BN+sigmoid -> bf16 h4
    gemm_fp8(abuf, 3, f8buf, 0);
    agg_fp8_kernel<2><<<ablocks, 256, 0, stream>>>(f8buf, row_ptr, e8,
        bvec[3], g[3], be[3], mm[3], vv[3], hbuf, n, 1);
    // L5 (128->128): GEMM5 raw -> fp8 hw5, agg-last fp8 128 + bias+sigmoid -> bf16 h5
    gemm_fp8(hbuf, 4, f8buf, 0);
    agg_fp8_kernel<2><<<ablocks, 256, 0, stream>>>(f8buf, row_ptr, e8,
        bvec[4], bvec[4], bvec[4], bvec[4], bvec[4], abuf, n, 2);

    // final h^T h with zeroed diagonal (MFMA)
    htht_mfma_kernel<<<KCH, 256, 0, stream>>>(abuf, partial, n);
    reduce_kernel<<<16384 / 256, 256, 0, stream>>>(partial, (float*)d_out, KCH);
}